// Round 12
// baseline (1356.794 us; speedup 1.0000x reference)
//
#include <hip/hip_runtime.h>
#include <hip/hip_bf16.h>

typedef __hip_bfloat16 bf16;
typedef __attribute__((ext_vector_type(8))) short short8;
typedef __attribute__((ext_vector_type(4))) short short4v;
typedef __attribute__((ext_vector_type(4))) float f32x4;

#define AS1 __attribute__((address_space(1)))
#define AS3 __attribute__((address_space(3)))

#define B_  8
#define N_  512
#define D_  512
#define H_  8
#define DH_ 64
#define DF_ 2048
#define L_  4

static __device__ __forceinline__ short bfbits(float x) {
  bf16 t = __float2bfloat16(x);
  return *reinterpret_cast<short*>(&t);
}

// ---------------- input prep (both tensors in one dispatch, float4) ----------------
__global__ __launch_bounds__(256) void k_prep2(const float* __restrict__ a,
                                               float* __restrict__ fa, bf16* __restrict__ ba,
                                               const float* __restrict__ bsrc,
                                               float* __restrict__ fb, bf16* __restrict__ bb,
                                               int n4) {
  int g = blockIdx.x * 256 + threadIdx.x;
  const float* s; float* f; bf16* o; long idx;
  if (g < n4) { s = a;    f = fa; o = ba; idx = (long)g * 4; }
  else        { s = bsrc; f = fb; o = bb; idx = (long)(g - n4) * 4; }
  float4 v = *(const float4*)(s + idx);
  *(float4*)(f + idx) = v;
  bf16 ov[4] = { __float2bfloat16(v.x), __float2bfloat16(v.y),
                 __float2bfloat16(v.z), __float2bfloat16(v.w) };
  *(short4v*)&o[idx] = *(const short4v*)ov;
}

// ---------------- per-layer weight transpose + cast (float4 in, short4 out) ----------------
__global__ __launch_bounds__(256) void k_wt(const float* __restrict__ aw_l,
                                            const float* __restrict__ awo_l,
                                            const float* __restrict__ fw1_l,
                                            const float* __restrict__ fw2_l,
                                            bf16* __restrict__ WT)
{
  __shared__ float Ls[32][33];
  int bx = blockIdx.x;
  const float* src; bf16* dst; int R, C, tr, tc;
  if (bx < 4096) {
    int id = bx >> 8, t = bx & 255;
    int m = id >> 2, part = id & 3;
    src = (part < 3) ? (aw_l + ((long)m * 3 + part) * D_ * D_)
                     : (awo_l + (long)m * D_ * D_);
    dst = WT + (long)id * 262144; R = 512; C = 512; tr = t >> 4; tc = t & 15;
  } else if (bx < 6144) {
    int q = bx - 4096; int id = q >> 10; int t = q & 1023;
    src = fw1_l + (long)id * D_ * DF_; dst = WT + 4194304 + (long)id * 1048576;
    R = 512; C = 2048; tr = t >> 6; tc = t & 63;
  } else {
    int q = bx - 6144; int id = q >> 10; int t = q & 1023;
    src = fw2_l + (long)id * DF_ * D_; dst = WT + 6291456 + (long)id * 1048576;
    R = 2048; C = 512; tr = t >> 4; tc = t & 15;
  }
  int t = threadIdx.x;
  int lr = t >> 3, lc0 = (t & 7) * 4;
  float4 v = *(const float4*)(src + (long)(tr * 32 + lr) * C + tc * 32 + lc0);
  Ls[lr][lc0] = v.x; Ls[lr][lc0 + 1] = v.y; Ls[lr][lc0 + 2] = v.z; Ls[lr][lc0 + 3] = v.w;
  __syncthreads();
  bf16 ov[4];
#pragma unroll
  for (int j = 0; j < 4; ++j) ov[j] = __float2bfloat16(Ls[lc0 + j][lr]);
  *(short4v*)&dst[(long)(tc * 32 + lr) * R + tr * 32 + lc0] = *(const short4v*)ov;
}

// ---------------- MFMA GEMM, BK=64 two-plane K-loop (one barrier pair / 2 K-steps).
// C = A @ B^T, both [rows][K-contig] bf16. mode 1 = fused QKV routing.
// kSplit>1: partial kk -> Cf + kk*pStride, bias only in kk==0.
// T1 XCD swizzle (mode-0 GEMMs only): each XCD (= linear_id % 8) owns a contiguous
// row-band x all cols. R10: remap cut fc1-class FETCH 78->17MB, total -103us.
// R10/R11: QKV (mode 1) regressed 40->64us under the remap, invariant to intra-XCD
// order (R11 null) -> latency-bound QKV prefers the default scattered mapping's
// channel-level parallelism. So the remap is gated to mode==0.
// Bijective when gridDim.y % 8 == 0; identity otherwise (final-pool GEMMs).
template<int BN>
__global__ __launch_bounds__(256, 2) void k_mfma(
    const bf16* __restrict__ A, const bf16* __restrict__ A2,
    long aS, long aB, long aH, int lda,
    const bf16* __restrict__ Bm, long bS, long bB, long bH, int ldb,
    const float* __restrict__ bias, long biasS, float scale, int relu,
    float* __restrict__ Cf, long cfS, long cfB, long cfH, int ldcf,
    bf16* __restrict__ Cb, long cbS, long cbB, long cbH, int ldcb,
    int kLen, int Hh, int zPerS, int mode, int kSplit, long pStride)
{
  constexpr int MI = (BN == 128) ? 4 : 2;
  constexpr int NI = 4;
  __shared__ short As[2 * 128 * 32];       // two BK=32 planes, m97 layout each
  __shared__ short Bs[2 * BN * 32];
  int tid = threadIdx.x;
  int w = tid >> 6, lane = tid & 63;
  int z = blockIdx.z;
  int kk = 0;
  if (kSplit > 1) { kk = z % kSplit; z /= kSplit; }
  int s = z / zPerS; int zz = z - s * zPerS;
  int zb = zz / Hh, zh = zz - zb * Hh;
  // ---- XCD-aware (row-band) block remap, mode-0 only ----
  int gx = gridDim.x, gy = gridDim.y;
  int bxs = blockIdx.x, bys = blockIdx.y;
  if (((gy & 7) == 0) && mode == 0) {
    int Hf = blockIdx.x + gx * blockIdx.y;   // hardware linear id within z-slice
    int xcd = Hf & 7, j = Hf >> 3;           // j in [0, gx*rpx)
    int rpx = gy >> 3;                       // row-blocks per XCD
    bxs = j % gx;
    bys = xcd * rpx + j / gx;
  }
  int row0 = bys * 128;
  int col0 = bxs * BN;
  const bf16* Asel = (mode == 1 && col0 >= 512) ? A2 : A;
  const bf16* Ab = Asel + s * aS + zb * aB + zh * aH + (long)kk * kLen;
  const bf16* Bb = Bm + s * bS + zb * bB + zh * bH + (long)kk * kLen;
  int rw = (BN == 128) ? ((w >> 1) * 64) : (w * 32);
  int cw = (BN == 128) ? ((w & 1) * 64) : 0;
  int quad = lane >> 4, l16 = lane & 15;

  f32x4 acc[MI][NI];
#pragma unroll
  for (int i = 0; i < MI; ++i)
#pragma unroll
    for (int j = 0; j < NI; ++j) acc[i][j] = {0.f, 0.f, 0.f, 0.f};

  for (int k0 = 0; k0 < kLen; k0 += 64) {
#pragma unroll
    for (int hf = 0; hf < 2; ++hf) {
#pragma unroll
      for (int i = 0; i < 2; ++i) {        // A plane hf: 8 KB
        int o = i * 4096 + w * 1024 + lane * 16;
        int r = o >> 6;
        const bf16* g = Ab + (long)(row0 + r) * lda + k0 + hf * 32 + ((o & 63) >> 1);
        char* lp = (char*)As + hf * 8192 + i * 4096 + w * 1024;
        __builtin_amdgcn_global_load_lds((const AS1 void*)g, (AS3 void*)lp, 16, 0, 0);
      }
      constexpr int BI = (BN == 128) ? 2 : 1;
#pragma unroll
      for (int i = 0; i < BI; ++i) {       // B plane hf
        int o = i * 4096 + w * 1024 + lane * 16;
        int r = o >> 6;
        const bf16* g = Bb + (long)(col0 + r) * ldb + k0 + hf * 32 + ((o & 63) >> 1);
        char* lp = (char*)Bs + hf * (BN * 64) + i * 4096 + w * 1024;
        __builtin_amdgcn_global_load_lds((const AS1 void*)g, (AS3 void*)lp, 16, 0, 0);
      }
    }
    __syncthreads();
#pragma unroll
    for (int hf = 0; hf < 2; ++hf) {
      short8 af[MI], bfr[NI];
#pragma unroll
      for (int mi = 0; mi < MI; ++mi)
        af[mi] = *(const short8*)&As[hf * 4096 + (rw + mi * 16 + l16) * 32 + quad * 8];
#pragma unroll
      for (int ni = 0; ni < NI; ++ni)
        bfr[ni] = *(const short8*)&Bs[hf * (BN * 32) + (cw + ni * 16 + l16) * 32 + quad * 8];
#pragma unroll
      for (int mi = 0; mi < MI; ++mi)
#pragma unroll
        for (int ni = 0; ni < NI; ++ni)
          acc[mi][ni] = __builtin_amdgcn_mfma_f32_16x16x32_bf16(af[mi], bfr[ni], acc[mi][ni], 0, 0, 0);
    }
    __syncthreads();
  }

  const float* bp = (bias && kk == 0) ? bias + s * biasS : nullptr;
#pragma unroll
  for (int mi = 0; mi < MI; ++mi)
#pragma unroll
    for (int ni = 0; ni < NI; ++ni) {
      int cg = col0 + cw + ni * 16 + l16;
      float bv = bp ? bp[cg] : 0.0f;
#pragma unroll
      for (int r = 0; r < 4; ++r) {
        int rg = row0 + rw + mi * 16 + quad * 4 + r;
        float v = acc[mi][ni][r] * scale + bv;
        if (relu) v = fmaxf(v, 0.0f);
        if (mode == 1) {
          bf16* base = Cb + s * cbS;
          if (cg < 512) base[(long)rg * 512 + cg] = __float2bfloat16(v);
          else if (cg < 1024) base[2097152 + (long)rg * 512 + (cg - 512)] = __float2bfloat16(v);
          else {
            int c2 = cg - 1024;
            base[4194304 + ((long)((rg >> 9) * 8 + (c2 >> 6)) * 64 + (c2 & 63)) * 512 + (rg & 511)]
                = __float2bfloat16(v);
          }
        } else {
          if (Cf) Cf[s * cfS + (long)kk * pStride + zb * cfB + zh * cfH + (long)rg * ldcf + cg] = v;
          if (Cb) Cb[s * cbS + zb * cbB + zh * cbH + (long)rg * ldcb + cg] = __float2bfloat16(v);
        }
      }
    }
}

// ---------------- flash attention ----------------
// pre-PV barrier removed (Ps rows are same-warp write->read only); setprio around MFMA.
// T1 XCD swizzle: XCD (= linear_id % 8) owns 8 bh values x all qt, so each (b,h)
// K/V panel (128 KB) is fetched by exactly one XCD (8 panels = 1 MB per L2).
__global__ __launch_bounds__(256, 2) void k_flash(
    const bf16* __restrict__ QKV, long sStride,
    const int* __restrict__ km0, const int* __restrict__ km1, float scale)
{
  __shared__ short Ks[2 * 128 * 32];
  __shared__ short Vs[4 * 64 * 32];
  __shared__ short Ps[4 * 64 * 32];
  int tid = threadIdx.x, w = tid >> 6, lane = tid & 63;
  int quad = lane >> 4, l16 = lane & 15;
  int s = blockIdx.z;
  const bf16* base = QKV + s * sStride;
  // ---- XCD-aware block remap (grid y is always 64 = 8 bh per XCD) ----
  int Hf = blockIdx.x + gridDim.x * blockIdx.y;
  int xcd = Hf & 7, j8 = Hf >> 3;
  int bh = xcd * 8 + (j8 & 7);
  int qt = j8 >> 3;
  int b = bh >> 3, h = bh & 7;
  const int* km = (s ? km1 : km0) + (b << 9);
  const bf16* Kg = base + 2097152;
  const bf16* Vt = base + 4194304;
  bf16* Og = (bf16*)base;

  int qrow = (b << 9) + (qt << 6) + (w << 4) + l16;
  short8 qf[2];
  qf[0] = *(const short8*)&base[(long)qrow * 512 + h * 64 + quad * 8];
  qf[1] = *(const short8*)&base[(long)qrow * 512 + h * 64 + 32 + quad * 8];

  float m_[4], l_[4];
  f32x4 acc_o[4];
#pragma unroll
  for (int r = 0; r < 4; ++r) { m_[r] = -3e38f; l_[r] = 0.f; }
#pragma unroll
  for (int ni = 0; ni < 4; ++ni) acc_o[ni] = {0.f, 0.f, 0.f, 0.f};

  for (int kt = 0; kt < 4; ++kt) {
    __syncthreads();
#pragma unroll
    for (int i = 0; i < 4; ++i) {
      int o = i * 4096 + w * 1024 + lane * 16;
      int kc = o >> 13, rem = o & 8191;
      int n = rem >> 6, cb = rem & 63;
      const bf16* g = Kg + ((long)((b << 9) + kt * 128 + n) << 9) + h * 64 + kc * 32 + (cb >> 1);
      char* lp = (char*)Ks + i * 4096 + w * 1024;
      __builtin_amdgcn_global_load_lds((const AS1 void*)g, (AS3 void*)lp, 16, 0, 0);
    }
#pragma unroll
    for (int i = 0; i < 4; ++i) {
      int o = i * 4096 + w * 1024 + lane * 16;
      int kc = o >> 12, rem = o & 4095;
      int d = rem >> 6, cb = rem & 63;
      const bf16* g = Vt + ((long)((bh << 6) + d) << 9) + kt * 128 + kc * 32 + (cb >> 1);
      char* lp = (char*)Vs + i * 4096 + w * 1024;
      __builtin_amdgcn_global_load_lds((const AS1 void*)g, (AS3 void*)lp, 16, 0, 0);
    }
    __syncthreads();
    f32x4 sa[8];
#pragma unroll
    for (int ni = 0; ni < 8; ++ni) sa[ni] = {0.f, 0.f, 0.f, 0.f};
    __builtin_amdgcn_s_setprio(1);
#pragma unroll
    for (int kc = 0; kc < 2; ++kc)
#pragma unroll
      for (int ni = 0; ni < 8; ++ni) {
        short8 bfrag = *(const short8*)&Ks[kc * 4096 + (ni * 16 + l16) * 32 + quad * 8];
        sa[ni] = __builtin_amdgcn_mfma_f32_16x16x32_bf16(qf[kc], bfrag, sa[ni], 0, 0, 0);
      }
    __builtin_amdgcn_s_setprio(0);
    float sv[8][4];
#pragma unroll
    for (int ni = 0; ni < 8; ++ni) {
      int kmv = km[kt * 128 + ni * 16 + l16];
#pragma unroll
      for (int r = 0; r < 4; ++r)
        sv[ni][r] = kmv ? sa[ni][r] * scale : -1e9f;
    }
#pragma unroll
    for (int r = 0; r < 4; ++r) {
      float rmax = sv[0][r];
#pragma unroll
      for (int ni = 1; ni < 8; ++ni) rmax = fmaxf(rmax, sv[ni][r]);
#pragma unroll
      for (int o = 1; o < 16; o <<= 1) rmax = fmaxf(rmax, __shfl_xor(rmax, o, 64));
      float newm = fmaxf(m_[r], rmax);
      float alpha = __expf(m_[r] - newm);
      float psum = 0.f;
#pragma unroll
      for (int ni = 0; ni < 8; ++ni) {
        float p = __expf(sv[ni][r] - newm);
        sv[ni][r] = p; psum += p;
      }
#pragma unroll
      for (int o = 1; o < 16; o <<= 1) psum += __shfl_xor(psum, o, 64);
      l_[r] = l_[r] * alpha + psum;
      m_[r] = newm;
#pragma unroll
      for (int ni = 0; ni < 4; ++ni) acc_o[ni][r] *= alpha;
    }
#pragma unroll
    for (int ni = 0; ni < 8; ++ni) {
      int j = ni * 16 + l16;
      short* pp = &Ps[(j >> 5) * 2048 + (w * 16 + quad * 4) * 32 + (j & 31)];
#pragma unroll
      for (int r = 0; r < 4; ++r) pp[r * 32] = bfbits(sv[ni][r]);
    }
    // no __syncthreads(): Ps rows [w*16, w*16+16) are same-warp write->read only.
    __builtin_amdgcn_s_setprio(1);
#pragma unroll
    for (int kcp = 0; kcp < 4; ++kcp) {
      short8 af = *(const short8*)&Ps[kcp * 2048 + (w * 16 + l16) * 32 + quad * 8];
#pragma unroll
      for (int ni = 0; ni < 4; ++ni) {
        short8 bfrag = *(const short8*)&Vs[kcp * 2048 + (ni * 16 + l16) * 32 + quad * 8];
        acc_o[ni] = __builtin_amdgcn_mfma_f32_16x16x32_bf16(af, bfrag, acc_o[ni], 0, 0, 0);
      }
    }
    __builtin_amdgcn_s_setprio(0);
  }
  float linv[4];
#pragma unroll
  for (int r = 0; r < 4; ++r) linv[r] = 1.0f / l_[r];
#pragma unroll
  for (int ni = 0; ni < 4; ++ni)
#pragma unroll
    for (int r = 0; r < 4; ++r) {
      long row = (b << 9) + (qt << 6) + (w << 4) + quad * 4 + r;
      Og[row * 512 + h * 64 + ni * 16 + l16] = __float2bfloat16(acc_o[ni][r] * linv[r]);
    }
}

// ---------------- fused dual LN over two split-K partials (2 rows/block, float4) ----------------
__global__ __launch_bounds__(256) void k_ln2(
    const float* x0, const float* g0, const float* b0, float* yf0, bf16* yb0,
    const float* x1, const float* g1, const float* b1, float* yf1, bf16* yb1,
    const float* __restrict__ P, long pstr)
{
  int t = threadIdx.x;
  int rh = t >> 7;                            // which of the block's 2 rows
  long row = (long)blockIdx.x * 2 + rh;       // 0..8191
  int sel = row >= 4096;
  long r = row & 4095;
  const float* x  = sel ? x1 : x0;
  const float* g  = sel ? g1 : g0;
  const float* bb = sel ? b1 : b0;
  float* yf = sel ? yf1 : yf0;
  bf16*  yb = sel ? yb1 : yb0;
  int c = (t & 127) * 4;
  const float* xr = x + r * D_ + c;
  const float* ra = P + (sel ? 2 : 0) * pstr + r * D_ + c;
  const float* rb = ra + pstr;
  float4 xv = *(const float4*)xr;
  float4 av = *(const float4*)ra;
  float4 bv = *(const float4*)rb;
  float4 v = { xv.x + av.x + bv.x, xv.y + av.y + bv.y,
               xv.z + av.z + bv.z, xv.w + av.w + bv.w };
  float s  = v.x + v.y + v.z + v.w;
  float ss = v.x * v.x + v.y * v.y + v.z * v.z + v.w * v.w;
#pragma unroll
  for (int o = 32; o > 0; o >>= 1) {
    s  += __shfl_down(s, o, 64);
    ss += __shfl_down(ss, o, 64);
  }
  __shared__ float rs[4];
  __shared__ float rss[4];
  int lane = t & 63, wid = t >> 6;
  if (lane == 0) { rs[wid] = s; rss[wid] = ss; }
  __syncthreads();
  s  = rs[rh * 2]  + rs[rh * 2 + 1];
  ss = rss[rh * 2] + rss[rh * 2 + 1];
  float mean = s * (1.0f / D_);
  float var = ss * (1.0f / D_) - mean * mean;
  float rstd = rsqrtf(var + 1e-5f);
  float4 gg = *(const float4*)(g + c);
  float4 b4 = *(const float4*)(bb + c);
  float4 o4 = { (v.x - mean) * rstd * gg.x + b4.x,
                (v.y - mean) * rstd * gg.y + b4.y,
                (v.z - mean) * rstd * gg.z + b4.z,
                (v.w - mean) * rstd * gg.w + b4.w };
  if (yf) *(float4*)(yf + r * D_ + c) = o4;
  if (yb) {
    bf16 ov[4] = { __float2bfloat16(o4.x), __float2bfloat16(o4.y),
                   __float2bfloat16(o4.z), __float2bfloat16(o4.w) };
    *(short4v*)&yb[r * D_ + c] = *(const short4v*)ov;
  }
}

// ---------------- sum two fp32 partials -> bf16 ----------------
__global__ __launch_bounds__(256) void k_sum2bf(const float* __restrict__ a,
                                                const float* __restrict__ b,
                                                bf16* __restrict__ o)
{
  int i = (blockIdx.x * 256 + threadIdx.x) * 4;
  float4 va = *(const float4*)(a + i);
  float4 vb = *(const float4*)(b + i);
  bf16 ov[4] = { __float2bfloat16(va.x + vb.x), __float2bfloat16(va.y + vb.y),
                 __float2bfloat16(va.z + vb.z), __float2bfloat16(va.w + vb.w) };
  *(short4v*)&o[i] = *(const short4v*)ov;
}

// ---------------- wave-per-row cross-masked softmax (final pooling) ----------------
__global__ __launch_bounds__(256) void k_softmax_x(float* __restrict__ S,
                                                   const int* __restrict__ vm,
                                                   const int* __restrict__ qm)
{
  int wrow = blockIdx.x * 4 + (threadIdx.x >> 6);
  int lane = threadIdx.x & 63;
  int b = wrow >> 9, i = wrow & 511;
  bool rowpad = (vm[(b << 9) + i] == 0);
  float* p = S + (long)wrow * 512;
  const int* qb = qm + (b << 9);
  int j0 = lane * 8;
  float4 a0 = *(const float4*)(p + j0);
  float4 a1 = *(const float4*)(p + j0 + 4);
  int4 m0 = *(const int4*)(qb + j0);
  int4 m1 = *(const int4*)(qb + j0 + 4);
  float v[8];
  v[0] = (rowpad || !m0.x) ? -1e9f : a0.x; v[1] = (rowpad || !m0.y) ? -1e9f : a0.y;
  v[2] = (rowpad || !m0.z) ? -1e9f : a0.z; v[3] = (rowpad || !m0.w) ? -1e9f : a0.w;
  v[4] = (rowpad || !m1.x) ? -1e9f : a1.x; v[5] = (rowpad || !m1.y) ? -1e9f : a1.y;
  v[6] = (rowpad || !m1.z) ? -1e9f : a1.z; v[7] = (rowpad || !m1.w) ? -1e9f : a1.w;
  float mx = v[0];
#pragma unroll
  for (int u = 1; u < 8; ++u) mx = fmaxf(mx, v[u]);
#pragma unroll
  for (int o = 1; o < 64; o <<= 1) mx = fmaxf(mx, __shfl_xor(mx, o, 64));
  float e[8], sum = 0.f;
#pragma unroll
  for (int u = 0; u < 8; ++u) { e[u] = __expf(v[u] - mx); sum += e[u]; }
#pragma unroll
  for (int o = 1; o < 64; o <<= 1) sum += __shfl_xor(sum, o, 64);
  float inv = 1.0f / sum;
  bf16 ob[8];
#pragma unroll
  for (int u = 0; u < 8; ++u) ob[u] = __float2bfloat16(e[u] * inv);
  bf16* pb = (bf16*)p;
  *(short8*)&pb[j0] = *(const short8*)ob;
}

// ---------------- final prep: Vw = bf16(V*w); Qt = bf16(Q^T) per batch ----------------
__global__ __launch_bounds__(256) void k_vwqt(const float* __restrict__ V,
                                              const float* __restrict__ Q,
                                              const float* __restrict__ w,
                                              bf16* __restrict__ Vw, bf16* __restrict__ Qt)
{
  __shared__ float Ls[32][33];
  int bx = blockIdx.x, t = threadIdx.x;
  if (bx < 2048) {
    int i = bx * 1024 + t * 4;
    float4 v = *(const float4*)(V + i);
    int k = i & 511;
    bf16 o[4] = { __float2bfloat16(v.x * w[k]),     __float2bfloat16(v.y * w[k + 1]),
                  __float2bfloat16(v.z * w[k + 2]), __float2bfloat16(v.w * w[k + 3]) };
    *(short4v*)&Vw[i] = *(const short4v*)o;
  } else {
    int q = bx - 2048; int b = q >> 8; int tq = q & 255;
    int tr = tq >> 4, tc = tq & 15;
    const float* Qb = Q + (long)b * 262144;
    bf16* Qtb = Qt + (long)b * 262144;
    int lr = t >> 3, lc0 = (t & 7) * 4;
    float4 v = *(const float4*)(Qb + (long)(tr * 32 + lr) * 512 + tc * 32 + lc0);
    Ls[lr][lc0] = v.x; Ls[lr][lc0 + 1] = v.y; Ls[lr][lc0 + 2] = v.z; Ls[lr][lc0 + 3] = v.w;
    __syncthreads();
    bf16 ov[4];
#pragma unroll
    for (int j = 0; j < 4; ++j) ov[j] = __float2bfloat16(Ls[lc0 + j][lr]);
    *(short4v*)&Qtb[(long)(tc * 32 + lr) * 512 + tr * 32 + lc0] = *(const short4v*)ov;
  }
}

// ---------------- out[b,k] = (1/512) * sum_i V[b,i,k] * T[b,i,k] ----------------
// split over 16 i-segments x 2 k-halves x 8 batches = 256 blocks -> partials, then reduce
__global__ __launch_bounds__(256) void k_final_part(
    const float* __restrict__ V, const float* __restrict__ QT, float* __restrict__ Pf)
{
  int bx = blockIdx.x;
  int b = bx >> 5, rem = bx & 31;
  int kc = rem >> 4, is = rem & 15;
  int k = (kc << 8) + threadIdx.x;
  const float* Vb = V  + (long)b * N_ * D_ + (long)(is * 32) * D_ + k;
  const float* Tb = QT + (long)b * N_ * D_ + (long)(is * 32) * D_ + k;
  float acc = 0.0f;
#pragma unroll 8
  for (int i = 0; i < 32; ++i) acc += Vb[(long)i * D_] * Tb[(long)i * D_];
  Pf[bx * 256 + threadIdx.x] = acc;
}

__global__ __launch_bounds__(256) void k_fred(const float* __restrict__ Pf,
                                              float* __restrict__ out)
{
  int b = blockIdx.x >> 1, kc = blockIdx.x & 1;
  int k = (kc << 8) + threadIdx.x;
  float s = 0.0f;
#pragma unroll
  for (int is = 0; is < 16; ++is)
    s += Pf[(((b << 5) | (kc << 4) | is) << 8) + threadIdx.x];
  out[b * D_ + k] = s * (1.0f / 512.0f);
}

extern "C" void kernel_launch(void* const* d_in, const int* in_sizes, int n_in,
                              void* d_out, int out_size, void* d_ws, size_t ws_size,
                              hipStream_t stream)
{
  const float* in_v   = (const float*)d_in[0];
  const float* in_q   = (const float*)d_in[1];
  const int*   v_mask = (const int*)  d_in[2];
  const int*   q_mask = (const int*)  d_in[3];
  const float* aw  = (const float*)d_in[4];
  const float* ab  = (const float*)d_in[5];
  const float* awo = (const float*)d_in[6];
  const float* abo = (const float*)d_in[7];
  const float* lg  = (const float*)d_in[8];
  const float* lb  = (const float*)d_in[9];
  const float* fw1 = (const float*)d_in[10];
  const float* fb1 = (const float*)d_in[11];
  const float* fw2 = (const float*)d_in[12];
  const float* fb2 = (const float*)d_in[13];
  const float* atw = (const float*)d_in[14];
  const float* atb = (const float*)d_in[15];
  float* out = (float*)d_out;
  (void)atb;  // softmax is shift-invariant

  const int SZ = B_ * N_ * D_;
  char* wsb = (char*)d_ws;
  const long MB = 1024L * 1024;
  float* Vcur   = (float*)(wsb + 0 * MB);
  float* Qcur   = (float*)(wsb + 8 * MB);
  float* P0     = (float*)(wsb + 16 * MB);
  const long PSZ = 2097152;               // floats per partial (8 MB)
  bf16*  WT     = (bf16*) (wsb + 48 * MB);
  bf16*  Vcur_b = (bf16*) (wsb + 64 * MB);
  bf16*  Qcur_b = (bf16*) (wsb + 68 * MB);
  bf16*  VA_b   = (bf16*) (wsb + 72 * MB);
  bf16*  QA_b   = (bf16*) (wsb + 76 * MB);
  bf16*  VQ_b   = (bf16*) (wsb + 80 * MB);
  bf16*  QKV0   = (bf16*) (wsb + 84 * MB);
  bf16*  Hid    = (bf16*) (wsb + 108 * MB);
  float* Sf     = P0;
  bf16*  Vw_b   = (bf16*) (wsb + 24 * MB);
  bf16*  Qt_b   = (bf16*) (wsb + 28 * MB);
  float* Tfin   = (float*)(wsb + 32 * MB);
  float* Pf     = (float*)(wsb + 41 * MB);   // 256 KB final-pool partials

  const long ZBIG = 1000000;

  k_prep2<<<4096, 256, 0, stream>>>(in_v, Vcur, Vcur_b, in_q, Qcur, Qcur_b, SZ / 4);

  for (int l = 0; l < L_; ++l) {
    const float* lgl = lg + (long)l * 6 * D_;
    const float* lbl = lb + (long)l * 6 * D_;
    k_wt<<<8192, 256, 0, stream>>>(aw + (long)l * 12 * 262144,
                                   awo + (long)l * 4 * 262144,
                                   fw1 + (long)l * 2 * 1048576,
                                   fw2 + (long)l * 2 * 1048576, WT);
    // ---- self-attention (2 streams: s0=v, s1=q) ----
    k_mfma<128><<<dim3(12, 32, 2), 256, 0, stream>>>(
        Vcur_b, Vcur_b, 2097152, 0, 0, 512,
        WT, 1048576, 0, 0, 512,
        ab + (long)l * 4 * 1536, 1536, 1.f, 0,
        nullptr, 0, 0, 0, 0, QKV0, 6291456, 0, 0, 0,
        512, 1, 1, 1, 1, 0);
    k_flash<<<dim3(8, 64, 2), 256, 0, stream>>>(QKV0, 6291456, v_mask, q_mask, 0.125f);
    k_mfma<128><<<dim3(4, 32, 4), 256, 0, stream>>>(      // out-proj, splitK=2 x 2 streams
        QKV0, QKV0, 6291456, 0, 0, 512,
        WT + 3 * 262144, 1048576, 0, 0, 512,
        abo + (long)l * 4 * 512, 512, 1.f, 0,
        P0, 2 * PSZ, 0, 0, 512, nullptr, 0, 0, 0, 0,
        256, 1, 1, 0, 2, PSZ);
    k_ln2<<<4096, 256, 0, stream>>>(Vcur, lgl + 0 * D_, lbl + 0 * D_, nullptr, VA_b,
                                    Qcur, lgl + 1 * D_, lbl + 1 * D_, nullptr, QA_b,
                                    P0, PSZ);
    // ---- cross attention vq: xq=VA, xkv=QA ----
    k_mfma<128><<<dim3(12, 32, 1), 256, 0, stream>>>(
        VA_b, QA_b, 0, 0, 0, 512,
        WT + 2 * 1048576, 0, 0, 0, 512,
        ab + (long)(l * 4 + 2) * 1536, 0, 1.f, 0,
        nullptr, 0, 0, 0, 0, QKV0, 0, 0, 0, 0,
        512, 1, 1, 1, 1, 0);
    k_flash<<<dim3(8, 64, 1), 256, 0, stream>>>(QKV0, 0, q_mask, q_mask, 0.125f);
    k_mfma<64><<<dim3(8, 32, 2), 256, 0, stream>>>(       // out-proj vq -> P0,P1
        QKV0, QKV0, 0, 0, 0, 512,
        WT + (2 * 4 + 3) * 262144, 0, 0, 0, 512,
        abo + (long)(l * 4 + 2) * 512, 0, 1.f, 0,
        P0, 0, 0, 0, 512, nullptr, 0, 0, 0, 0,
        256, 1, 1, 0, 2, PSZ);
    k_sum2bf<<<2048, 256, 0, stream>>>(P0, P0 + PSZ, VQ_b);
    // ---- cross attention qv: xq=QA, xkv=VQ ----
    k_mfma<128><<<dim3(12, 32, 1), 256, 0, stream>>>(
        QA_b, VQ_b, 0, 0, 0, 512,
        WT + 3 * 1048576, 0, 0, 0, 512,
        ab + (long)(l * 4 + 3) * 1536, 0, 1.f, 0,
        nullptr, 0, 0, 0, 0, QKV0, 0, 0, 0, 0,
        512, 1, 1, 1, 1, 0);
    k_flash<<<dim3(8, 64, 1), 256, 0, stream>>>(QKV0, 0, v_mask, v_mask, 0.125f);
    k_mfma<64><<<dim3(8, 32, 2), 256, 0, stream>>>(       // out-proj qv -> P2,P3
        QKV0, QKV0, 0, 0, 0, 512,
        WT + (3 * 4 + 3) * 262144, 0, 0, 0, 512,
        abo + (long)(l * 4 + 3) * 512, 0, 1.f, 0,
        P0 + 2 * PSZ, 0, 0, 0, 512, nullptr, 0, 0, 0, 0,
        256, 1, 1, 0, 2, PSZ);
    k_ln2<<<4096, 256, 0, stream>>>(Vcur, lgl + 2 * D_, lbl + 2 * D_, Vcur, Vcur_b,
                                    Qcur, lgl + 3 * D_, lbl + 3 * D_, Qcur, Qcur_b,
                                    P0, PSZ);
    // ---- FFN (2 streams) ----
    k_mfma<128><<<dim3(16, 32, 2), 256, 0, stream>>>(
        Vcur_b, Vcur_b, 2097152, 0, 0, 512,
        WT + 4194304, 1048576, 0, 0, 512,
        fb1 + (long)l * 2 * 2048, 2048, 1.f, 1,
        nullptr, 0, 0, 0, 0, Hid, 8388608, 0, 0, 2048,
        512, 1, 1, 0, 1, 0);
    k_mfma<128><<<dim3(4, 32, 4), 256, 0, stream>>>(      // fc2 splitK=2 x 2 streams
        Hid, Hid, 8388608, 0, 0, 2048,
        WT + 6291456, 1048576, 0, 0, 2048,
        fb2 + (long)l * 2 * 512, 512, 1.f, 0,
        P0, 2 * PSZ, 0, 0, 512, nullptr, 0, 0, 0, 0,
        1024, 1, 1, 0, 2, PSZ);
    k_ln2<<<4096, 256, 0, stream>>>(Vcur, lgl + 4 * D_, lbl + 4 * D_, Vcur, Vcur_b,
                                    Qcur, lgl + 5 * D_, lbl + 5 * D_, Qcur, Qcur_b,
                                    P0, PSZ);
  }

  // ---- final bilinear attention pooling ----
  k_vwqt<<<4096, 256, 0, stream>>>(Vcur, Qcur, atw, Vw_b, Qt_b);
  k_mfma<128><<<dim3(4, 4, 8), 256, 0, stream>>>(          // scores = (V*w) @ Q^T -> Sf(=P0)
      Vw_b, Vw_b, 0, 262144, 0, 512, Qcur_b, 0, 262144, 0, 512,
      nullptr, 0, 1.f, 0,
      Sf, 0, 262144, 0, 512, nullptr, 0, 0, 0, 0,
      512, 1, ZBIG, 0, 1, 0);
  k_softmax_x<<<1024, 256, 0, stream>>>(Sf, v_mask, q_mask);
  k_mfma<128><<<dim3(4, 4, 8), 256, 0, stream>>>(          // Tfin = P @ Q
      (const bf16*)Sf, (const bf16*)Sf, 0, 524288, 0, 1024, Qt_b, 0, 262144, 0, 512,
      nullptr, 0, 1.f, 0,
      Tfin, 0, 262144, 0, 512, nullptr, 0, 0, 0, 0,
      512, 1, ZBIG, 0, 1, 0);
  k_final_part<<<256, 256, 0, stream>>>(Vcur, Tfin, Pf);
  k_fred<<<16, 256, 0, stream>>>(Pf, out);

  (void)in_sizes; (void)n_in; (void)out_size; (void)ws_size;
}

// Round 14
// 1308.096 us; speedup vs baseline: 1.0372x; 1.0372x over previous
//
#include <hip/hip_runtime.h>
#include <hip/hip_bf16.h>

typedef __hip_bfloat16 bf16;
typedef __attribute__((ext_vector_type(8))) short short8;
typedef __attribute__((ext_vector_type(4))) short short4v;
typedef __attribute__((ext_vector_type(4))) float f32x4;

#define AS1 __attribute__((address_space(1)))
#define AS3 __attribute__((address_space(3)))

#define B_  8
#define N_  512
#define D_  512
#define H_  8
#define DH_ 64
#define DF_ 2048
#define L_  4

static __device__ __forceinline__ short bfbits(float x) {
  bf16 t = __float2bfloat16(x);
  return *reinterpret_cast<short*>(&t);
}

static __device__ __forceinline__ unsigned packbf2(float lo, float hi) {
  bf16 a = __float2bfloat16(lo), b = __float2bfloat16(hi);
  unsigned short ua = *reinterpret_cast<unsigned short*>(&a);
  unsigned short ub = *reinterpret_cast<unsigned short*>(&b);
  return (unsigned)ua | ((unsigned)ub << 16);
}

// ---------------- input prep (both tensors in one dispatch, float4) ----------------
__global__ __launch_bounds__(256) void k_prep2(const float* __restrict__ a,
                                               float* __restrict__ fa, bf16* __restrict__ ba,
                                               const float* __restrict__ bsrc,
                                               float* __restrict__ fb, bf16* __restrict__ bb,
                                               int n4) {
  int g = blockIdx.x * 256 + threadIdx.x;
  const float* s; float* f; bf16* o; long idx;
  if (g < n4) { s = a;    f = fa; o = ba; idx = (long)g * 4; }
  else        { s = bsrc; f = fb; o = bb; idx = (long)(g - n4) * 4; }
  float4 v = *(const float4*)(s + idx);
  *(float4*)(f + idx) = v;
  bf16 ov[4] = { __float2bfloat16(v.x), __float2bfloat16(v.y),
                 __float2bfloat16(v.z), __float2bfloat16(v.w) };
  *(short4v*)&o[idx] = *(const short4v*)ov;
}

// ---------------- per-layer weight transpose + cast (float4 in, short4 out) ----------------
__global__ __launch_bounds__(256) void k_wt(const float* __restrict__ aw_l,
                                            const float* __restrict__ awo_l,
                                            const float* __restrict__ fw1_l,
                                            const float* __restrict__ fw2_l,
                                            bf16* __restrict__ WT)
{
  __shared__ float Ls[32][33];
  int bx = blockIdx.x;
  const float* src; bf16* dst; int R, C, tr, tc;
  if (bx < 4096) {
    int id = bx >> 8, t = bx & 255;
    int m = id >> 2, part = id & 3;
    src = (part < 3) ? (aw_l + ((long)m * 3 + part) * D_ * D_)
                     : (awo_l + (long)m * D_ * D_);
    dst = WT + (long)id * 262144; R = 512; C = 512; tr = t >> 4; tc = t & 15;
  } else if (bx < 6144) {
    int q = bx - 4096; int id = q >> 10; int t = q & 1023;
    src = fw1_l + (long)id * D_ * DF_; dst = WT + 4194304 + (long)id * 1048576;
    R = 512; C = 2048; tr = t >> 6; tc = t & 63;
  } else {
    int q = bx - 6144; int id = q >> 10; int t = q & 1023;
    src = fw2_l + (long)id * DF_ * D_; dst = WT + 6291456 + (long)id * 1048576;
    R = 2048; C = 512; tr = t >> 4; tc = t & 15;
  }
  int t = threadIdx.x;
  int lr = t >> 3, lc0 = (t & 7) * 4;
  float4 v = *(const float4*)(src + (long)(tr * 32 + lr) * C + tc * 32 + lc0);
  Ls[lr][lc0] = v.x; Ls[lr][lc0 + 1] = v.y; Ls[lr][lc0 + 2] = v.z; Ls[lr][lc0 + 3] = v.w;
  __syncthreads();
  bf16 ov[4];
#pragma unroll
  for (int j = 0; j < 4; ++j) ov[j] = __float2bfloat16(Ls[lc0 + j][lr]);
  *(short4v*)&dst[(long)(tc * 32 + lr) * R + tr * 32 + lc0] = *(const short4v*)ov;
}

// ---------------- MFMA GEMM, BK=64 two-plane K-loop (one barrier pair / 2 K-steps).
// C = A @ B^T, both [rows][K-contig] bf16. mode 1 = fused QKV routing.
// kSplit>1: partial kk -> Cf + kk*pStride, bias only in kk==0.
// T1 XCD swizzle (ALL modes — R12 showed QKV remap pays via producer->consumer
// L2 affinity with k_flash: XCD x writes K/V rows of batch x, flash XCD x reads
// batch x). R13: mode-1 V^T epilogue now goes through an LDS transpose so each
// thread writes 8x16B contiguous instead of 64x2B at 1KB stride (store-issue
// serialization was the 64us QKV cost under the row-band remap).
// Bijective when gridDim.y % 8 == 0; identity otherwise (final-pool GEMMs).
template<int BN>
__global__ __launch_bounds__(256, 2) void k_mfma(
    const bf16* __restrict__ A, const bf16* __restrict__ A2,
    long aS, long aB, long aH, int lda,
    const bf16* __restrict__ Bm, long bS, long bB, long bH, int ldb,
    const float* __restrict__ bias, long biasS, float scale, int relu,
    float* __restrict__ Cf, long cfS, long cfB, long cfH, int ldcf,
    bf16* __restrict__ Cb, long cbS, long cbB, long cbH, int ldcb,
    int kLen, int Hh, int zPerS, int mode, int kSplit, long pStride)
{
  constexpr int MI = (BN == 128) ? 4 : 2;
  constexpr int NI = 4;
  __shared__ short SMEM[16384];            // 32 KB: As(16K) | Bs(16K); reused as 128x128 T
  short* As = SMEM;
  short* Bs = SMEM + 8192;
  int tid = threadIdx.x;
  int w = tid >> 6, lane = tid & 63;
  int z = blockIdx.z;
  int kk = 0;
  if (kSplit > 1) { kk = z % kSplit; z /= kSplit; }
  int s = z / zPerS; int zz = z - s * zPerS;
  int zb = zz / Hh, zh = zz - zb * Hh;
  // ---- XCD-aware (row-band) block remap ----
  int gx = gridDim.x, gy = gridDim.y;
  int bxs = blockIdx.x, bys = blockIdx.y;
  if ((gy & 7) == 0) {
    int Hf = blockIdx.x + gx * blockIdx.y;   // hardware linear id within z-slice
    int xcd = Hf & 7, j = Hf >> 3;           // j in [0, gx*rpx)
    int rpx = gy >> 3;                       // row-blocks per XCD
    bxs = j % gx;
    bys = xcd * rpx + j / gx;
  }
  int row0 = bys * 128;
  int col0 = bxs * BN;
  const bf16* Asel = (mode == 1 && col0 >= 512) ? A2 : A;
  const bf16* Ab = Asel + s * aS + zb * aB + zh * aH + (long)kk * kLen;
  const bf16* Bb = Bm + s * bS + zb * bB + zh * bH + (long)kk * kLen;
  int rw = (BN == 128) ? ((w >> 1) * 64) : (w * 32);
  int cw = (BN == 128) ? ((w & 1) * 64) : 0;
  int quad = lane >> 4, l16 = lane & 15;

  f32x4 acc[MI][NI];
#pragma unroll
  for (int i = 0; i < MI; ++i)
#pragma unroll
    for (int j = 0; j < NI; ++j) acc[i][j] = {0.f, 0.f, 0.f, 0.f};

  for (int k0 = 0; k0 < kLen; k0 += 64) {
#pragma unroll
    for (int hf = 0; hf < 2; ++hf) {
#pragma unroll
      for (int i = 0; i < 2; ++i) {        // A plane hf: 8 KB
        int o = i * 4096 + w * 1024 + lane * 16;
        int r = o >> 6;
        const bf16* g = Ab + (long)(row0 + r) * lda + k0 + hf * 32 + ((o & 63) >> 1);
        char* lp = (char*)As + hf * 8192 + i * 4096 + w * 1024;
        __builtin_amdgcn_global_load_lds((const AS1 void*)g, (AS3 void*)lp, 16, 0, 0);
      }
      constexpr int BI = (BN == 128) ? 2 : 1;
#pragma unroll
      for (int i = 0; i < BI; ++i) {       // B plane hf
        int o = i * 4096 + w * 1024 + lane * 16;
        int r = o >> 6;
        const bf16* g = Bb + (long)(col0 + r) * ldb + k0 + hf * 32 + ((o & 63) >> 1);
        char* lp = (char*)Bs + hf * (BN * 64) + i * 4096 + w * 1024;
        __builtin_amdgcn_global_load_lds((const AS1 void*)g, (AS3 void*)lp, 16, 0, 0);
      }
    }
    __syncthreads();
#pragma unroll
    for (int hf = 0; hf < 2; ++hf) {
      short8 af[MI], bfr[NI];
#pragma unroll
      for (int mi = 0; mi < MI; ++mi)
        af[mi] = *(const short8*)&As[hf * 4096 + (rw + mi * 16 + l16) * 32 + quad * 8];
#pragma unroll
      for (int ni = 0; ni < NI; ++ni)
        bfr[ni] = *(const short8*)&Bs[hf * (BN * 32) + (cw + ni * 16 + l16) * 32 + quad * 8];
#pragma unroll
      for (int mi = 0; mi < MI; ++mi)
#pragma unroll
        for (int ni = 0; ni < NI; ++ni)
          acc[mi][ni] = __builtin_amdgcn_mfma_f32_16x16x32_bf16(af[mi], bfr[ni], acc[mi][ni], 0, 0, 0);
    }
    __syncthreads();
  }

  const float* bp = (bias && kk == 0) ? bias + s * biasS : nullptr;

  // ---- mode-1 V col-blocks: LDS-transposed coalesced epilogue ----
  if (mode == 1 && col0 >= 1024) {
    unsigned* T32 = (unsigned*)SMEM;       // T[128 cols][128 rows] bf16, row-xor swizzled
#pragma unroll
    for (int mi = 0; mi < MI; ++mi)
#pragma unroll
      for (int ni = 0; ni < NI; ++ni) {
        int col_l = cw + ni * 16 + l16;
        float bv = bp ? bp[col0 + col_l] : 0.0f;
        int xorc = (col_l & 7) << 4;
#pragma unroll
        for (int r = 0; r < 4; r += 2) {
          int row_l = rw + mi * 16 + quad * 4 + r;          // even
          float v0 = acc[mi][ni][r] * scale + bv;
          float v1 = acc[mi][ni][r + 1] * scale + bv;
          T32[(col_l * 128 + (row_l ^ xorc)) >> 1] = packbf2(v0, v1);
        }
      }
    __syncthreads();
    int col_r = tid >> 1, rhalf = (tid & 1) << 6;
    int c2 = col0 - 1024 + col_r;
    int batch = row0 >> 9;                                  // block spans one batch
    bf16* dstp = Cb + s * cbS + 4194304
               + ((long)(batch * 8 + (c2 >> 6)) * 64 + (c2 & 63)) * 512
               + (row0 & 511) + rhalf;
    int xr = (col_r & 7) << 4;
#pragma unroll
    for (int g = 0; g < 4; ++g) {
      int rb = (rhalf + g * 16) ^ xr;                       // 16-aligned; xor only bits 4-6
      short8 v0 = *(const short8*)&SMEM[col_r * 128 + rb];
      short8 v1 = *(const short8*)&SMEM[col_r * 128 + rb + 8];
      *(short8*)&dstp[g * 16] = v0;
      *(short8*)&dstp[g * 16 + 8] = v1;
    }
    return;
  }

#pragma unroll
  for (int mi = 0; mi < MI; ++mi)
#pragma unroll
    for (int ni = 0; ni < NI; ++ni) {
      int cg = col0 + cw + ni * 16 + l16;
      float bv = bp ? bp[cg] : 0.0f;
#pragma unroll
      for (int r = 0; r < 4; ++r) {
        int rg = row0 + rw + mi * 16 + quad * 4 + r;
        float v = acc[mi][ni][r] * scale + bv;
        if (relu) v = fmaxf(v, 0.0f);
        if (mode == 1) {
          bf16* base = Cb + s * cbS;
          if (cg < 512) base[(long)rg * 512 + cg] = __float2bfloat16(v);
          else base[2097152 + (long)rg * 512 + (cg - 512)] = __float2bfloat16(v);
        } else {
          if (Cf) Cf[s * cfS + (long)kk * pStride + zb * cfB + zh * cfH + (long)rg * ldcf + cg] = v;
          if (Cb) Cb[s * cbS + zb * cbB + zh * cbH + (long)rg * ldcb + cg] = __float2bfloat16(v);
        }
      }
    }
}

// ---------------- flash attention ----------------
// pre-PV barrier removed (Ps rows are same-warp write->read only); setprio around MFMA.
// T1 XCD swizzle: XCD (= linear_id % 8) owns 8 bh values x all qt, so each (b,h)
// K/V panel (128 KB) is fetched by exactly one XCD (8 panels = 1 MB per L2).
__global__ __launch_bounds__(256, 2) void k_flash(
    const bf16* __restrict__ QKV, long sStride,
    const int* __restrict__ km0, const int* __restrict__ km1, float scale)
{
  __shared__ short Ks[2 * 128 * 32];
  __shared__ short Vs[4 * 64 * 32];
  __shared__ short Ps[4 * 64 * 32];
  int tid = threadIdx.x, w = tid >> 6, lane = tid & 63;
  int quad = lane >> 4, l16 = lane & 15;
  int s = blockIdx.z;
  const bf16* base = QKV + s * sStride;
  // ---- XCD-aware block remap (grid y is always 64 = 8 bh per XCD) ----
  int Hf = blockIdx.x + gridDim.x * blockIdx.y;
  int xcd = Hf & 7, j8 = Hf >> 3;
  int bh = xcd * 8 + (j8 & 7);
  int qt = j8 >> 3;
  int b = bh >> 3, h = bh & 7;
  const int* km = (s ? km1 : km0) + (b << 9);
  const bf16* Kg = base + 2097152;
  const bf16* Vt = base + 4194304;
  bf16* Og = (bf16*)base;

  int qrow = (b << 9) + (qt << 6) + (w << 4) + l16;
  short8 qf[2];
  qf[0] = *(const short8*)&base[(long)qrow * 512 + h * 64 + quad * 8];
  qf[1] = *(const short8*)&base[(long)qrow * 512 + h * 64 + 32 + quad * 8];

  float m_[4], l_[4];
  f32x4 acc_o[4];
#pragma unroll
  for (int r = 0; r < 4; ++r) { m_[r] = -3e38f; l_[r] = 0.f; }
#pragma unroll
  for (int ni = 0; ni < 4; ++ni) acc_o[ni] = {0.f, 0.f, 0.f, 0.f};

  for (int kt = 0; kt < 4; ++kt) {
    __syncthreads();
#pragma unroll
    for (int i = 0; i < 4; ++i) {
      int o = i * 4096 + w * 1024 + lane * 16;
      int kc = o >> 13, rem = o & 8191;
      int n = rem >> 6, cb = rem & 63;
      const bf16* g = Kg + ((long)((b << 9) + kt * 128 + n) << 9) + h * 64 + kc * 32 + (cb >> 1);
      char* lp = (char*)Ks + i * 4096 + w * 1024;
      __builtin_amdgcn_global_load_lds((const AS1 void*)g, (AS3 void*)lp, 16, 0, 0);
    }
#pragma unroll
    for (int i = 0; i < 4; ++i) {
      int o = i * 4096 + w * 1024 + lane * 16;
      int kc = o >> 12, rem = o & 4095;
      int d = rem >> 6, cb = rem & 63;
      const bf16* g = Vt + ((long)((bh << 6) + d) << 9) + kt * 128 + kc * 32 + (cb >> 1);
      char* lp = (char*)Vs + i * 4096 + w * 1024;
      __builtin_amdgcn_global_load_lds((const AS1 void*)g, (AS3 void*)lp, 16, 0, 0);
    }
    __syncthreads();
    f32x4 sa[8];
#pragma unroll
    for (int ni = 0; ni < 8; ++ni) sa[ni] = {0.f, 0.f, 0.f, 0.f};
    __builtin_amdgcn_s_setprio(1);
#pragma unroll
    for (int kc = 0; kc < 2; ++kc)
#pragma unroll
      for (int ni = 0; ni < 8; ++ni) {
        short8 bfrag = *(const short8*)&Ks[kc * 4096 + (ni * 16 + l16) * 32 + quad * 8];
        sa[ni] = __builtin_amdgcn_mfma_f32_16x16x32_bf16(qf[kc], bfrag, sa[ni], 0, 0, 0);
      }
    __builtin_amdgcn_s_setprio(0);
    float sv[8][4];
#pragma unroll
    for (int ni = 0; ni < 8; ++ni) {
      int kmv = km[kt * 128 + ni * 16 + l16];
#pragma unroll
      for (int r = 0; r < 4; ++r)
        sv[ni][r] = kmv ? sa[ni][r] * scale : -1e9f;
    }
#pragma unroll
    for (int r = 0; r < 4; ++r) {
      float rmax = sv[0][r];
#pragma unroll
      for (int ni = 1; ni < 8; ++ni) rmax = fmaxf(rmax, sv[ni][r]);
#pragma unroll
      for (int o = 1; o < 16; o <<= 1) rmax = fmaxf(rmax, __shfl_xor(rmax, o, 64));
      float newm = fmaxf(m_[r], rmax);
      float alpha = __expf(m_[r] - newm);
      float psum = 0.f;
#pragma unroll
      for (int ni = 0; ni < 8; ++ni) {
        float p = __expf(sv[ni][r] - newm);
        sv[ni][r] = p; psum += p;
      }
#pragma unroll
      for (int o = 1; o < 16; o <<= 1) psum += __shfl_xor(psum, o, 64);
      l_[r] = l_[r] * alpha + psum;
      m_[r] = newm;
#pragma unroll
      for (int ni = 0; ni < 4; ++ni) acc_o[ni][r] *= alpha;
    }
#pragma unroll
    for (int ni = 0; ni < 8; ++ni) {
      int j = ni * 16 + l16;
      short* pp = &Ps[(j >> 5) * 2048 + (w * 16 + quad * 4) * 32 + (j & 31)];
#pragma unroll
      for (int r = 0; r < 4; ++r) pp[r * 32] = bfbits(sv[ni][r]);
    }
    // no __syncthreads(): Ps rows [w*16, w*16+16) are same-warp write->read only.
    __builtin_amdgcn_s_setprio(1);
#pragma unroll
    for (int kcp = 0; kcp < 4; ++kcp) {
      short8 af = *(const short8*)&Ps[kcp * 2048 + (w * 16 + l16) * 32 + quad * 8];
#pragma unroll
      for (int ni = 0; ni < 4; ++ni) {
        short8 bfrag = *(const short8*)&Vs[kcp * 2048 + (ni * 16 + l16) * 32 + quad * 8];
        acc_o[ni] = __builtin_amdgcn_mfma_f32_16x16x32_bf16(af, bfrag, acc_o[ni], 0, 0, 0);
      }
    }
    __builtin_amdgcn_s_setprio(0);
  }
  float linv[4];
#pragma unroll
  for (int r = 0; r < 4; ++r) linv[r] = 1.0f / l_[r];
#pragma unroll
  for (int ni = 0; ni < 4; ++ni)
#pragma unroll
    for (int r = 0; r < 4; ++r) {
      long row = (b << 9) + (qt << 6) + (w << 4) + quad * 4 + r;
      Og[row * 512 + h * 64 + ni * 16 + l16] = __float2bfloat16(acc_o[ni][r] * linv[r]);
    }
}

// ---------------- fused dual LN over two split-K partials (2 rows/block, float4) ----------------
__global__ __launch_bounds__(256) void k_ln2(
    const float* x0, const float* g0, const float* b0, float* yf0, bf16* yb0,
    const float* x1, const float* g1, const float* b1, float* yf1, bf16* yb1,
    const float* __restrict__ P, long pstr)
{
  int t = threadIdx.x;
  int rh = t >> 7;                            // which of the block's 2 rows
  long row = (long)blockIdx.x * 2 + rh;       // 0..8191
  int sel = row >= 4096;
  long r = row & 4095;
  const float* x  = sel ? x1 : x0;
  const float* g  = sel ? g1 : g0;
  const float* bb = sel ? b1 : b0;
  float* yf = sel ? yf1 : yf0;
  bf16*  yb = sel ? yb1 : yb0;
  int c = (t & 127) * 4;
  const float* xr = x + r * D_ + c;
  const float* ra = P + (sel ? 2 : 0) * pstr + r * D_ + c;
  const float* rb = ra + pstr;
  float4 xv = *(const float4*)xr;
  float4 av = *(const float4*)ra;
  float4 bv = *(const float4*)rb;
  float4 v = { xv.x + av.x + bv.x, xv.y + av.y + bv.y,
               xv.z + av.z + bv.z, xv.w + av.w + bv.w };
  float s  = v.x + v.y + v.z + v.w;
  float ss = v.x * v.x + v.y * v.y + v.z * v.z + v.w * v.w;
#pragma unroll
  for (int o = 32; o > 0; o >>= 1) {
    s  += __shfl_down(s, o, 64);
    ss += __shfl_down(ss, o, 64);
  }
  __shared__ float rs[4];
  __shared__ float rss[4];
  int lane = t & 63, wid = t >> 6;
  if (lane == 0) { rs[wid] = s; rss[wid] = ss; }
  __syncthreads();
  s  = rs[rh * 2]  + rs[rh * 2 + 1];
  ss = rss[rh * 2] + rss[rh * 2 + 1];
  float mean = s * (1.0f / D_);
  float var = ss * (1.0f / D_) - mean * mean;
  float rstd = rsqrtf(var + 1e-5f);
  float4 gg = *(const float4*)(g + c);
  float4 b4 = *(const float4*)(bb + c);
  float4 o4 = { (v.x - mean) * rstd * gg.x + b4.x,
                (v.y - mean) * rstd * gg.y + b4.y,
                (v.z - mean) * rstd * gg.z + b4.z,
                (v.w - mean) * rstd * gg.w + b4.w };
  if (yf) *(float4*)(yf + r * D_ + c) = o4;
  if (yb) {
    bf16 ov[4] = { __float2bfloat16(o4.x), __float2bfloat16(o4.y),
                   __float2bfloat16(o4.z), __float2bfloat16(o4.w) };
    *(short4v*)&yb[r * D_ + c] = *(const short4v*)ov;
  }
}

// ---------------- sum two fp32 partials -> bf16 ----------------
__global__ __launch_bounds__(256) void k_sum2bf(const float* __restrict__ a,
                                                const float* __restrict__ b,
                                                bf16* __restrict__ o)
{
  int i = (blockIdx.x * 256 + threadIdx.x) * 4;
  float4 va = *(const float4*)(a + i);
  float4 vb = *(const float4*)(b + i);
  bf16 ov[4] = { __float2bfloat16(va.x + vb.x), __float2bfloat16(va.y + vb.y),
                 __float2bfloat16(va.z + vb.z), __float2bfloat16(va.w + vb.w) };
  *(short4v*)&o[i] = *(const short4v*)ov;
}

// ---------------- wave-per-row cross-masked softmax (final pooling) ----------------
__global__ __launch_bounds__(256) void k_softmax_x(float* __restrict__ S,
                                                   const int* __restrict__ vm,
                                                   const int* __restrict__ qm)
{
  int wrow = blockIdx.x * 4 + (threadIdx.x >> 6);
  int lane = threadIdx.x & 63;
  int b = wrow >> 9, i = wrow & 511;
  bool rowpad = (vm[(b << 9) + i] == 0);
  float* p = S + (long)wrow * 512;
  const int* qb = qm + (b << 9);
  int j0 = lane * 8;
  float4 a0 = *(const float4*)(p + j0);
  float4 a1 = *(const float4*)(p + j0 + 4);
  int4 m0 = *(const int4*)(qb + j0);
  int4 m1 = *(const int4*)(qb + j0 + 4);
  float v[8];
  v[0] = (rowpad || !m0.x) ? -1e9f : a0.x; v[1] = (rowpad || !m0.y) ? -1e9f : a0.y;
  v[2] = (rowpad || !m0.z) ? -1e9f : a0.z; v[3] = (rowpad || !m0.w) ? -1e9f : a0.w;
  v[4] = (rowpad || !m1.x) ? -1e9f : a1.x; v[5] = (rowpad || !m1.y) ? -1e9f : a1.y;
  v[6] = (rowpad || !m1.z) ? -1e9f : a1.z; v[7] = (rowpad || !m1.w) ? -1e9f : a1.w;
  float mx = v[0];
#pragma unroll
  for (int u = 1; u < 8; ++u) mx = fmaxf(mx, v[u]);
#pragma unroll
  for (int o = 1; o < 64; o <<= 1) mx = fmaxf(mx, __shfl_xor(mx, o, 64));
  float e[8], sum = 0.f;
#pragma unroll
  for (int u = 0; u < 8; ++u) { e[u] = __expf(v[u] - mx); sum += e[u]; }
#pragma unroll
  for (int o = 1; o < 64; o <<= 1) sum += __shfl_xor(sum, o, 64);
  float inv = 1.0f / sum;
  bf16 ob[8];
#pragma unroll
  for (int u = 0; u < 8; ++u) ob[u] = __float2bfloat16(e[u] * inv);
  bf16* pb = (bf16*)p;
  *(short8*)&pb[j0] = *(const short8*)ob;
}

// ---------------- final prep: Vw = bf16(V*w); Qt = bf16(Q^T) per batch ----------------
__global__ __launch_bounds__(256) void k_vwqt(const float* __restrict__ V,
                                              const float* __restrict__ Q,
                                              const float* __restrict__ w,
                                              bf16* __restrict__ Vw, bf16* __restrict__ Qt)
{
  __shared__ float Ls[32][33];
  int bx = blockIdx.x, t = threadIdx.x;
  if (bx < 2048) {
    int i = bx * 1024 + t * 4;
    float4 v = *(const float4*)(V + i);
    int k = i & 511;
    bf16 o[4] = { __float2bfloat16(v.x * w[k]),     __float2bfloat16(v.y * w[k + 1]),
                  __float2bfloat16(v.z * w[k + 2]), __float2bfloat16(v.w * w[k + 3]) };
    *(short4v*)&Vw[i] = *(const short4v*)o;
  } else {
    int q = bx - 2048; int b = q >> 8; int tq = q & 255;
    int tr = tq >> 4, tc = tq & 15;
    const float* Qb = Q + (long)b * 262144;
    bf16* Qtb = Qt + (long)b * 262144;
    int lr = t >> 3, lc0 = (t & 7) * 4;
    float4 v = *(const float4*)(Qb + (long)(tr * 32 + lr) * 512 + tc * 32 + lc0);
    Ls[lr][lc0] = v.x; Ls[lr][lc0 + 1] = v.y; Ls[lr][lc0 + 2] = v.z; Ls[lr][lc0 + 3] = v.w;
    __syncthreads();
    bf16 ov[4];
#pragma unroll
    for (int j = 0; j < 4; ++j) ov[j] = __float2bfloat16(Ls[lc0 + j][lr]);
    *(short4v*)&Qtb[(long)(tc * 32 + lr) * 512 + tr * 32 + lc0] = *(const short4v*)ov;
  }
}

// ---------------- out[b,k] = (1/512) * sum_i V[b,i,k] * T[b,i,k] ----------------
// split over 16 i-segments x 2 k-halves x 8 batches = 256 blocks -> partials, then reduce
__global__ __launch_bounds__(256) void k_final_part(
    const float* __restrict__ V, const float* __restrict__ QT, float* __restrict__ Pf)
{
  int bx = blockIdx.x;
  int b = bx >> 5, rem = bx & 31;
  int kc = rem >> 4, is = rem & 15;
  int k = (kc << 8) + threadIdx.x;
  const float* Vb = V  + (long)b * N_ * D_ + (long)(is * 32) * D_ + k;
  const float* Tb = QT + (long)b * N_ * D_ + (long)(is * 32) * D_ + k;
  float acc = 0.0f;
#pragma unroll 8
  for (int i = 0; i < 32; ++i) acc += Vb[(long)i * D_] * Tb[(long)i * D_];
  Pf[bx * 256 + threadIdx.x] = acc;
}

__global__ __launch_bounds__(256) void k_fred(const float* __restrict__ Pf,
                                              float* __restrict__ out)
{
  int b = blockIdx.x >> 1, kc = blockIdx.x & 1;
  int k = (kc << 8) + threadIdx.x;
  float s = 0.0f;
#pragma unroll
  for (int is = 0; is < 16; ++is)
    s += Pf[(((b << 5) | (kc << 4) | is) << 8) + threadIdx.x];
  out[b * D_ + k] = s * (1.0f / 512.0f);
}

extern "C" void kernel_launch(void* const* d_in, const int* in_sizes, int n_in,
                              void* d_out, int out_size, void* d_ws, size_t ws_size,
                              hipStream_t stream)
{
  const float* in_v   = (const float*)d_in[0];
  const float* in_q   = (const float*)d_in[1];
  const int*   v_mask = (const int*)  d_in[2];
  const int*   q_mask = (const int*)  d_in[3];
  const float* aw  = (const float*)d_in[4];
  const float* ab  = (const float*)d_in[5];
  const float* awo = (const float*)d_in[6];
  const float* abo = (const float*)d_in[7];
  const float* lg  = (const float*)d_in[8];
  const float* lb  = (const float*)d_in[9];
  const float* fw1 = (const float*)d_in[10];
  const float* fb1 = (const float*)d_in[11];
  const float* fw2 = (const float*)d_in[12];
  const float* fb2 = (const float*)d_in[13];
  const float* atw = (const float*)d_in[14];
  const float* atb = (const float*)d_in[15];
  float* out = (float*)d_out;
  (void)atb;  // softmax is shift-invariant

  const int SZ = B_ * N_ * D_;
  char* wsb = (char*)d_ws;
  const long MB = 1024L * 1024;
  float* Vcur   = (float*)(wsb + 0 * MB);
  float* Qcur   = (float*)(wsb + 8 * MB);
  float* P0     = (float*)(wsb + 16 * MB);
  const long PSZ = 2097152;               // floats per partial (8 MB)
  bf16*  WT     = (bf16*) (wsb + 48 * MB);
  bf16*  Vcur_b = (bf16*) (wsb + 64 * MB);
  bf16*  Qcur_b = (bf16*) (wsb + 68 * MB);
  bf16*  VA_b   = (bf16*) (wsb + 72 * MB);
  bf16*  QA_b   = (bf16*) (wsb + 76 * MB);
  bf16*  VQ_b   = (bf16*) (wsb + 80 * MB);
  bf16*  QKV0   = (bf16*) (wsb + 84 * MB);
  bf16*  Hid    = (bf16*) (wsb + 108 * MB);
  float* Sf     = P0;
  bf16*  Vw_b   = (bf16*) (wsb + 24 * MB);
  bf16*  Qt_b   = (bf16*) (wsb + 28 * MB);
  float* Tfin   = (float*)(wsb + 32 * MB);
  float* Pf     = (float*)(wsb + 41 * MB);   // 256 KB final-pool partials

  const long ZBIG = 1000000;

  k_prep2<<<4096, 256, 0, stream>>>(in_v, Vcur, Vcur_b, in_q, Qcur, Qcur_b, SZ / 4);

  for (int l = 0; l < L_; ++l) {
    const float* lgl = lg + (long)l * 6 * D_;
    const float* lbl = lb + (long)l * 6 * D_;
    k_wt<<<8192, 256, 0, stream>>>(aw + (long)l * 12 * 262144,
                                   awo + (long)l * 4 * 262144,
                                   fw1 + (long)l * 2 * 1048576,
                                   fw2 + (long)l * 2 * 1048576, WT);
    // ---- self-attention (2 streams: s0=v, s1=q) ----
    k_mfma<128><<<dim3(12, 32, 2), 256, 0, stream>>>(
        Vcur_b, Vcur_b, 2097152, 0, 0, 512,
        WT, 1048576, 0, 0, 512,
        ab + (long)l * 4 * 1536, 1536, 1.f, 0,
        nullptr, 0, 0, 0, 0, QKV0, 6291456, 0, 0, 0,
        512, 1, 1, 1, 1, 0);
    k_flash<<<dim3(8, 64, 2), 256, 0, stream>>>(QKV0, 6291456, v_mask, q_mask, 0.125f);
    k_mfma<128><<<dim3(4, 32, 4), 256, 0, stream>>>(      // out-proj, splitK=2 x 2 streams
        QKV0, QKV0, 6291456, 0, 0, 512,
        WT + 3 * 262144, 1048576, 0, 0, 512,
        abo + (long)l * 4 * 512, 512, 1.f, 0,
        P0, 2 * PSZ, 0, 0, 512, nullptr, 0, 0, 0, 0,
        256, 1, 1, 0, 2, PSZ);
    k_ln2<<<4096, 256, 0, stream>>>(Vcur, lgl + 0 * D_, lbl + 0 * D_, nullptr, VA_b,
                                    Qcur, lgl + 1 * D_, lbl + 1 * D_, nullptr, QA_b,
                                    P0, PSZ);
    // ---- cross attention vq: xq=VA, xkv=QA ----
    k_mfma<128><<<dim3(12, 32, 1), 256, 0, stream>>>(
        VA_b, QA_b, 0, 0, 0, 512,
        WT + 2 * 1048576, 0, 0, 0, 512,
        ab + (long)(l * 4 + 2) * 1536, 0, 1.f, 0,
        nullptr, 0, 0, 0, 0, QKV0, 0, 0, 0, 0,
        512, 1, 1, 1, 1, 0);
    k_flash<<<dim3(8, 64, 1), 256, 0, stream>>>(QKV0, 0, q_mask, q_mask, 0.125f);
    k_mfma<64><<<dim3(8, 32, 2), 256, 0, stream>>>(       // out-proj vq -> P0,P1
        QKV0, QKV0, 0, 0, 0, 512,
        WT + (2 * 4 + 3) * 262144, 0, 0, 0, 512,
        abo + (long)(l * 4 + 2) * 512, 0, 1.f, 0,
        P0, 0, 0, 0, 512, nullptr, 0, 0, 0, 0,
        256, 1, 1, 0, 2, PSZ);
    k_sum2bf<<<2048, 256, 0, stream>>>(P0, P0 + PSZ, VQ_b);
    // ---- cross attention qv: xq=QA, xkv=VQ ----
    k_mfma<128><<<dim3(12, 32, 1), 256, 0, stream>>>(
        QA_b, VQ_b, 0, 0, 0, 512,
        WT + 3 * 1048576, 0, 0, 0, 512,
        ab + (long)(l * 4 + 3) * 1536, 0, 1.f, 0,
        nullptr, 0, 0, 0, 0, QKV0, 0, 0, 0, 0,
        512, 1, 1, 1, 1, 0);
    k_flash<<<dim3(8, 64, 1), 256, 0, stream>>>(QKV0, 0, v_mask, v_mask, 0.125f);
    k_mfma<64><<<dim3(8, 32, 2), 256, 0, stream>>>(       // out-proj qv -> P2,P3
        QKV0, QKV0, 0, 0, 0, 512,
        WT + (3 * 4 + 3) * 262144, 0, 0, 0, 512,
        abo + (long)(l * 4 + 3) * 512, 0, 1.f, 0,
        P0 + 2 * PSZ, 0, 0, 0, 512, nullptr, 0, 0, 0, 0,
        256, 1, 1, 0, 2, PSZ);
    k_ln2<<<4096, 256, 0, stream>>>(Vcur, lgl + 2 * D_, lbl + 2 * D_, Vcur, Vcur_b,
                                    Qcur, lgl + 3 * D_, lbl + 3 * D_, Qcur, Qcur_b,
                                    P0, PSZ);
    // ---- FFN (2 streams) ----
    k_mfma<128><<<dim3(16, 32, 2), 256, 0, stream>>>(
        Vcur_b, Vcur_b, 2097152, 0, 0, 512,
        WT + 4194304, 1048576, 0, 0, 512,
        fb1 + (long)l * 2 * 2048, 2048, 1.f, 1,
        nullptr, 0, 0, 0, 0, Hid, 8388608, 0, 0, 2048,
        512, 1, 1, 0, 1, 0);
    k_mfma<128><<<dim3(4, 32, 4), 256, 0, stream>>>(      // fc2 splitK=2 x 2 streams
        Hid, Hid, 8388608, 0, 0, 2048,
        WT + 6291456, 1048576, 0, 0, 2048,
        fb2 + (long)l * 2 * 512, 512, 1.f, 0,
        P0, 2 * PSZ, 0, 0, 512, nullptr, 0, 0, 0, 0,
        1024, 1, 1, 0, 2, PSZ);
    k_ln2<<<4096, 256, 0, stream>>>(Vcur, lgl + 4 * D_, lbl + 4 * D_, Vcur, Vcur_b,
                                    Qcur, lgl + 5 * D_, lbl + 5 * D_, Qcur, Qcur_b,
                                    P0, PSZ);
  }

  // ---- final bilinear attention pooling ----
  k_vwqt<<<4096, 256, 0, stream>>>(Vcur, Qcur, atw, Vw_b, Qt_b);
  k_mfma<128><<<dim3(4, 4, 8), 256, 0, stream>>>(          // scores = (V*w) @ Q^T -> Sf(=P0)
      Vw_b, Vw_b, 0, 262144, 0, 512, Qcur_b, 0, 262144, 0, 512,
      nullptr, 0, 1.f, 0,
      Sf, 0, 262144, 0, 512, nullptr, 0, 0, 0, 0,
      512, 1, ZBIG, 0, 1, 0);
  k_softmax_x<<<1024, 256, 0, stream>>>(Sf, v_mask, q_mask);
  k_mfma<128><<<dim3(4, 4, 8), 256, 0, stream>>>(          // Tfin = P @ Q
      (const bf16*)Sf, (const bf16*)Sf, 0, 524288, 0, 1024, Qt_b, 0, 262144, 0, 512,
      nullptr, 0, 1.f, 0,
      Tfin, 0, 262144, 0, 512, nullptr, 0, 0, 0, 0,
      512, 1, ZBIG, 0, 1, 0);
  k_final_part<<<256, 256, 0, stream>>>(Vcur, Tfin, Pf);
  k_fred<<<16, 256, 0, stream>>>(Pf, out);

  (void)in_sizes; (void)n_in; (void)out_size; (void)ws_size;
}

// Round 15
// 1299.936 us; speedup vs baseline: 1.0437x; 1.0063x over previous
//
#include <hip/hip_runtime.h>
#include <hip/hip_bf16.h>

typedef __hip_bfloat16 bf16;
typedef __attribute__((ext_vector_type(8))) short short8;
typedef __attribute__((ext_vector_type(4))) short short4v;
typedef __attribute__((ext_vector_type(4))) float f32x4;

#define AS1 __attribute__((address_space(1)))
#define AS3 __attribute__((address_space(3)))

#define B_  8
#define N_  512
#define D_  512
#define H_  8
#define DH_ 64
#define DF_ 2048
#define L_  4

static __device__ __forceinline__ short bfbits(float x) {
  bf16 t = __float2bfloat16(x);
  return *reinterpret_cast<short*>(&t);
}

static __device__ __forceinline__ unsigned packbf2(float lo, float hi) {
  bf16 a = __float2bfloat16(lo), b = __float2bfloat16(hi);
  unsigned short ua = *reinterpret_cast<unsigned short*>(&a);
  unsigned short ub = *reinterpret_cast<unsigned short*>(&b);
  return (unsigned)ua | ((unsigned)ub << 16);
}

// ---------------- input prep (both tensors in one dispatch, float4) ----------------
__global__ __launch_bounds__(256) void k_prep2(const float* __restrict__ a,
                                               float* __restrict__ fa, bf16* __restrict__ ba,
                                               const float* __restrict__ bsrc,
                                               float* __restrict__ fb, bf16* __restrict__ bb,
                                               int n4) {
  int g = blockIdx.x * 256 + threadIdx.x;
  const float* s; float* f; bf16* o; long idx;
  if (g < n4) { s = a;    f = fa; o = ba; idx = (long)g * 4; }
  else        { s = bsrc; f = fb; o = bb; idx = (long)(g - n4) * 4; }
  float4 v = *(const float4*)(s + idx);
  *(float4*)(f + idx) = v;
  bf16 ov[4] = { __float2bfloat16(v.x), __float2bfloat16(v.y),
                 __float2bfloat16(v.z), __float2bfloat16(v.w) };
  *(short4v*)&o[idx] = *(const short4v*)ov;
}

// ---------------- per-layer weight transpose + cast (float4 in, short4 out) ----------------
__global__ __launch_bounds__(256) void k_wt(const float* __restrict__ aw_l,
                                            const float* __restrict__ awo_l,
                                            const float* __restrict__ fw1_l,
                                            const float* __restrict__ fw2_l,
                                            bf16* __restrict__ WT)
{
  __shared__ float Ls[32][33];
  int bx = blockIdx.x;
  const float* src; bf16* dst; int R, C, tr, tc;
  if (bx < 4096) {
    int id = bx >> 8, t = bx & 255;
    int m = id >> 2, part = id & 3;
    src = (part < 3) ? (aw_l + ((long)m * 3 + part) * D_ * D_)
                     : (awo_l + (long)m * D_ * D_);
    dst = WT + (long)id * 262144; R = 512; C = 512; tr = t >> 4; tc = t & 15;
  } else if (bx < 6144) {
    int q = bx - 4096; int id = q >> 10; int t = q & 1023;
    src = fw1_l + (long)id * D_ * DF_; dst = WT + 4194304 + (long)id * 1048576;
    R = 512; C = 2048; tr = t >> 6; tc = t & 63;
  } else {
    int q = bx - 6144; int id = q >> 10; int t = q & 1023;
    src = fw2_l + (long)id * DF_ * D_; dst = WT + 6291456 + (long)id * 1048576;
    R = 2048; C = 512; tr = t >> 4; tc = t & 15;
  }
  int t = threadIdx.x;
  int lr = t >> 3, lc0 = (t & 7) * 4;
  float4 v = *(const float4*)(src + (long)(tr * 32 + lr) * C + tc * 32 + lc0);
  Ls[lr][lc0] = v.x; Ls[lr][lc0 + 1] = v.y; Ls[lr][lc0 + 2] = v.z; Ls[lr][lc0 + 3] = v.w;
  __syncthreads();
  bf16 ov[4];
#pragma unroll
  for (int j = 0; j < 4; ++j) ov[j] = __float2bfloat16(Ls[lc0 + j][lr]);
  *(short4v*)&dst[(long)(tc * 32 + lr) * R + tr * 32 + lc0] = *(const short4v*)ov;
}

// ---------------- MFMA GEMM, BK=64 two-plane K-loop (one barrier pair / 2 K-steps).
// C = A @ B^T, both [rows][K-contig] bf16. mode 1 = fused QKV routing.
// kSplit>1: partial kk -> Cf + kk*pStride, bias only in kk==0.
// T1 XCD swizzle (all modes): producer->consumer L2 affinity with k_flash (R12).
// R13 LDS-transposed V^T epilogue (R14: QKV 64->52.6us).
template<int BN>
__global__ __launch_bounds__(256, 2) void k_mfma(
    const bf16* __restrict__ A, const bf16* __restrict__ A2,
    long aS, long aB, long aH, int lda,
    const bf16* __restrict__ Bm, long bS, long bB, long bH, int ldb,
    const float* __restrict__ bias, long biasS, float scale, int relu,
    float* __restrict__ Cf, long cfS, long cfB, long cfH, int ldcf,
    bf16* __restrict__ Cb, long cbS, long cbB, long cbH, int ldcb,
    int kLen, int Hh, int zPerS, int mode, int kSplit, long pStride)
{
  constexpr int MI = (BN == 128) ? 4 : 2;
  constexpr int NI = 4;
  __shared__ short SMEM[16384];            // 32 KB: As(16K) | Bs(16K); reused as 128x128 T
  short* As = SMEM;
  short* Bs = SMEM + 8192;
  int tid = threadIdx.x;
  int w = tid >> 6, lane = tid & 63;
  int z = blockIdx.z;
  int kk = 0;
  if (kSplit > 1) { kk = z % kSplit; z /= kSplit; }
  int s = z / zPerS; int zz = z - s * zPerS;
  int zb = zz / Hh, zh = zz - zb * Hh;
  // ---- XCD-aware (row-band) block remap ----
  int gx = gridDim.x, gy = gridDim.y;
  int bxs = blockIdx.x, bys = blockIdx.y;
  if ((gy & 7) == 0) {
    int Hf = blockIdx.x + gx * blockIdx.y;   // hardware linear id within z-slice
    int xcd = Hf & 7, j = Hf >> 3;           // j in [0, gx*rpx)
    int rpx = gy >> 3;                       // row-blocks per XCD
    bxs = j % gx;
    bys = xcd * rpx + j / gx;
  }
  int row0 = bys * 128;
  int col0 = bxs * BN;
  const bf16* Asel = (mode == 1 && col0 >= 512) ? A2 : A;
  const bf16* Ab = Asel + s * aS + zb * aB + zh * aH + (long)kk * kLen;
  const bf16* Bb = Bm + s * bS + zb * bB + zh * bH + (long)kk * kLen;
  int rw = (BN == 128) ? ((w >> 1) * 64) : (w * 32);
  int cw = (BN == 128) ? ((w & 1) * 64) : 0;
  int quad = lane >> 4, l16 = lane & 15;

  f32x4 acc[MI][NI];
#pragma unroll
  for (int i = 0; i < MI; ++i)
#pragma unroll
    for (int j = 0; j < NI; ++j) acc[i][j] = {0.f, 0.f, 0.f, 0.f};

  for (int k0 = 0; k0 < kLen; k0 += 64) {
#pragma unroll
    for (int hf = 0; hf < 2; ++hf) {
#pragma unroll
      for (int i = 0; i < 2; ++i) {        // A plane hf: 8 KB
        int o = i * 4096 + w * 1024 + lane * 16;
        int r = o >> 6;
        const bf16* g = Ab + (long)(row0 + r) * lda + k0 + hf * 32 + ((o & 63) >> 1);
        char* lp = (char*)As + hf * 8192 + i * 4096 + w * 1024;
        __builtin_amdgcn_global_load_lds((const AS1 void*)g, (AS3 void*)lp, 16, 0, 0);
      }
      constexpr int BI = (BN == 128) ? 2 : 1;
#pragma unroll
      for (int i = 0; i < BI; ++i) {       // B plane hf
        int o = i * 4096 + w * 1024 + lane * 16;
        int r = o >> 6;
        const bf16* g = Bb + (long)(col0 + r) * ldb + k0 + hf * 32 + ((o & 63) >> 1);
        char* lp = (char*)Bs + hf * (BN * 64) + i * 4096 + w * 1024;
        __builtin_amdgcn_global_load_lds((const AS1 void*)g, (AS3 void*)lp, 16, 0, 0);
      }
    }
    __syncthreads();
#pragma unroll
    for (int hf = 0; hf < 2; ++hf) {
      short8 af[MI], bfr[NI];
#pragma unroll
      for (int mi = 0; mi < MI; ++mi)
        af[mi] = *(const short8*)&As[hf * 4096 + (rw + mi * 16 + l16) * 32 + quad * 8];
#pragma unroll
      for (int ni = 0; ni < NI; ++ni)
        bfr[ni] = *(const short8*)&Bs[hf * (BN * 32) + (cw + ni * 16 + l16) * 32 + quad * 8];
#pragma unroll
      for (int mi = 0; mi < MI; ++mi)
#pragma unroll
        for (int ni = 0; ni < NI; ++ni)
          acc[mi][ni] = __builtin_amdgcn_mfma_f32_16x16x32_bf16(af[mi], bfr[ni], acc[mi][ni], 0, 0, 0);
    }
    __syncthreads();
  }

  const float* bp = (bias && kk == 0) ? bias + s * biasS : nullptr;

  // ---- mode-1 V col-blocks: LDS-transposed coalesced epilogue ----
  if (mode == 1 && col0 >= 1024) {
    unsigned* T32 = (unsigned*)SMEM;       // T[128 cols][128 rows] bf16, row-xor swizzled
#pragma unroll
    for (int mi = 0; mi < MI; ++mi)
#pragma unroll
      for (int ni = 0; ni < NI; ++ni) {
        int col_l = cw + ni * 16 + l16;
        float bv = bp ? bp[col0 + col_l] : 0.0f;
        int xorc = (col_l & 7) << 4;
#pragma unroll
        for (int r = 0; r < 4; r += 2) {
          int row_l = rw + mi * 16 + quad * 4 + r;          // even
          float v0 = acc[mi][ni][r] * scale + bv;
          float v1 = acc[mi][ni][r + 1] * scale + bv;
          T32[(col_l * 128 + (row_l ^ xorc)) >> 1] = packbf2(v0, v1);
        }
      }
    __syncthreads();
    int col_r = tid >> 1, rhalf = (tid & 1) << 6;
    int c2 = col0 - 1024 + col_r;
    int batch = row0 >> 9;                                  // block spans one batch
    bf16* dstp = Cb + s * cbS + 4194304
               + ((long)(batch * 8 + (c2 >> 6)) * 64 + (c2 & 63)) * 512
               + (row0 & 511) + rhalf;
    int xr = (col_r & 7) << 4;
#pragma unroll
    for (int g = 0; g < 4; ++g) {
      int rb = (rhalf + g * 16) ^ xr;                       // 16-aligned; xor only bits 4-6
      short8 v0 = *(const short8*)&SMEM[col_r * 128 + rb];
      short8 v1 = *(const short8*)&SMEM[col_r * 128 + rb + 8];
      *(short8*)&dstp[g * 16] = v0;
      *(short8*)&dstp[g * 16 + 8] = v1;
    }
    return;
  }

#pragma unroll
  for (int mi = 0; mi < MI; ++mi)
#pragma unroll
    for (int ni = 0; ni < NI; ++ni) {
      int cg = col0 + cw + ni * 16 + l16;
      float bv = bp ? bp[cg] : 0.0f;
#pragma unroll
      for (int r = 0; r < 4; ++r) {
        int rg = row0 + rw + mi * 16 + quad * 4 + r;
        float v = acc[mi][ni][r] * scale + bv;
        if (relu) v = fmaxf(v, 0.0f);
        if (mode == 1) {
          bf16* base = Cb + s * cbS;
          if (cg < 512) base[(long)rg * 512 + cg] = __float2bfloat16(v);
          else base[2097152 + (long)rg * 512 + (cg - 512)] = __float2bfloat16(v);
        } else {
          if (Cf) Cf[s * cfS + (long)kk * pStride + zb * cfB + zh * cfH + (long)rg * ldcf + cg] = v;
          if (Cb) Cb[s * cbS + zb * cbB + zh * cbH + (long)rg * ldcb + cg] = __float2bfloat16(v);
        }
      }
    }
}

// ---------------- flash attention ----------------
// pre-PV barrier removed (Ps rows are same-warp write->read only); setprio around MFMA.
// T1 XCD swizzle: XCD (= linear_id % 8) owns 8 bh values x all qt, so each (b,h)
// K/V panel (128 KB) is fetched by exactly one XCD (8 panels = 1 MB per L2).
__global__ __launch_bounds__(256, 2) void k_flash(
    const bf16* __restrict__ QKV, long sStride,
    const int* __restrict__ km0, const int* __restrict__ km1, float scale)
{
  __shared__ short Ks[2 * 128 * 32];
  __shared__ short Vs[4 * 64 * 32];
  __shared__ short Ps[4 * 64 * 32];
  int tid = threadIdx.x, w = tid >> 6, lane = tid & 63;
  int quad = lane >> 4, l16 = lane & 15;
  int s = blockIdx.z;
  const bf16* base = QKV + s * sStride;
  // ---- XCD-aware block remap (grid y is always 64 = 8 bh per XCD) ----
  int Hf = blockIdx.x + gridDim.x * blockIdx.y;
  int xcd = Hf & 7, j8 = Hf >> 3;
  int bh = xcd * 8 + (j8 & 7);
  int qt = j8 >> 3;
  int b = bh >> 3, h = bh & 7;
  const int* km = (s ? km1 : km0) + (b << 9);
  const bf16* Kg = base + 2097152;
  const bf16* Vt = base + 4194304;
  bf16* Og = (bf16*)base;

  int qrow = (b << 9) + (qt << 6) + (w << 4) + l16;
  short8 qf[2];
  qf[0] = *(const short8*)&base[(long)qrow * 512 + h * 64 + quad * 8];
  qf[1] = *(const short8*)&base[(long)qrow * 512 + h * 64 + 32 + quad * 8];

  float m_[4], l_[4];
  f32x4 acc_o[4];
#pragma unroll
  for (int r = 0; r < 4; ++r) { m_[r] = -3e38f; l_[r] = 0.f; }
#pragma unroll
  for (int ni = 0; ni < 4; ++ni) acc_o[ni] = {0.f, 0.f, 0.f, 0.f};

  for (int kt = 0; kt < 4; ++kt) {
    __syncthreads();
#pragma unroll
    for (int i = 0; i < 4; ++i) {
      int o = i * 4096 + w * 1024 + lane * 16;
      int kc = o >> 13, rem = o & 8191;
      int n = rem >> 6, cb = rem & 63;
      const bf16* g = Kg + ((long)((b << 9) + kt * 128 + n) << 9) + h * 64 + kc * 32 + (cb >> 1);
      char* lp = (char*)Ks + i * 4096 + w * 1024;
      __builtin_amdgcn_global_load_lds((const AS1 void*)g, (AS3 void*)lp, 16, 0, 0);
    }
#pragma unroll
    for (int i = 0; i < 4; ++i) {
      int o = i * 4096 + w * 1024 + lane * 16;
      int kc = o >> 12, rem = o & 4095;
      int d = rem >> 6, cb = rem & 63;
      const bf16* g = Vt + ((long)((bh << 6) + d) << 9) + kt * 128 + kc * 32 + (cb >> 1);
      char* lp = (char*)Vs + i * 4096 + w * 1024;
      __builtin_amdgcn_global_load_lds((const AS1 void*)g, (AS3 void*)lp, 16, 0, 0);
    }
    __syncthreads();
    f32x4 sa[8];
#pragma unroll
    for (int ni = 0; ni < 8; ++ni) sa[ni] = {0.f, 0.f, 0.f, 0.f};
    __builtin_amdgcn_s_setprio(1);
#pragma unroll
    for (int kc = 0; kc < 2; ++kc)
#pragma unroll
      for (int ni = 0; ni < 8; ++ni) {
        short8 bfrag = *(const short8*)&Ks[kc * 4096 + (ni * 16 + l16) * 32 + quad * 8];
        sa[ni] = __builtin_amdgcn_mfma_f32_16x16x32_bf16(qf[kc], bfrag, sa[ni], 0, 0, 0);
      }
    __builtin_amdgcn_s_setprio(0);
    float sv[8][4];
#pragma unroll
    for (int ni = 0; ni < 8; ++ni) {
      int kmv = km[kt * 128 + ni * 16 + l16];
#pragma unroll
      for (int r = 0; r < 4; ++r)
        sv[ni][r] = kmv ? sa[ni][r] * scale : -1e9f;
    }
#pragma unroll
    for (int r = 0; r < 4; ++r) {
      float rmax = sv[0][r];
#pragma unroll
      for (int ni = 1; ni < 8; ++ni) rmax = fmaxf(rmax, sv[ni][r]);
#pragma unroll
      for (int o = 1; o < 16; o <<= 1) rmax = fmaxf(rmax, __shfl_xor(rmax, o, 64));
      float newm = fmaxf(m_[r], rmax);
      float alpha = __expf(m_[r] - newm);
      float psum = 0.f;
#pragma unroll
      for (int ni = 0; ni < 8; ++ni) {
        float p = __expf(sv[ni][r] - newm);
        sv[ni][r] = p; psum += p;
      }
#pragma unroll
      for (int o = 1; o < 16; o <<= 1) psum += __shfl_xor(psum, o, 64);
      l_[r] = l_[r] * alpha + psum;
      m_[r] = newm;
#pragma unroll
      for (int ni = 0; ni < 4; ++ni) acc_o[ni][r] *= alpha;
    }
#pragma unroll
    for (int ni = 0; ni < 8; ++ni) {
      int j = ni * 16 + l16;
      short* pp = &Ps[(j >> 5) * 2048 + (w * 16 + quad * 4) * 32 + (j & 31)];
#pragma unroll
      for (int r = 0; r < 4; ++r) pp[r * 32] = bfbits(sv[ni][r]);
    }
    // no __syncthreads(): Ps rows [w*16, w*16+16) are same-warp write->read only.
    __builtin_amdgcn_s_setprio(1);
#pragma unroll
    for (int kcp = 0; kcp < 4; ++kcp) {
      short8 af = *(const short8*)&Ps[kcp * 2048 + (w * 16 + l16) * 32 + quad * 8];
#pragma unroll
      for (int ni = 0; ni < 4; ++ni) {
        short8 bfrag = *(const short8*)&Vs[kcp * 2048 + (ni * 16 + l16) * 32 + quad * 8];
        acc_o[ni] = __builtin_amdgcn_mfma_f32_16x16x32_bf16(af, bfrag, acc_o[ni], 0, 0, 0);
      }
    }
    __builtin_amdgcn_s_setprio(0);
  }
  float linv[4];
#pragma unroll
  for (int r = 0; r < 4; ++r) linv[r] = 1.0f / l_[r];
#pragma unroll
  for (int ni = 0; ni < 4; ++ni)
#pragma unroll
    for (int r = 0; r < 4; ++r) {
      long row = (b << 9) + (qt << 6) + (w << 4) + quad * 4 + r;
      Og[row * 512 + h * 64 + ni * 16 + l16] = __float2bfloat16(acc_o[ni][r] * linv[r]);
    }
}

// ---------------- fused dual LN over split-K partials (2 rows/block, float4).
// spmask: bit0 = v-half single-partial, bit1 = q-half single-partial.
__global__ __launch_bounds__(256) void k_ln2(
    const float* x0, const float* g0, const float* b0, float* yf0, bf16* yb0,
    const float* x1, const float* g1, const float* b1, float* yf1, bf16* yb1,
    const float* __restrict__ P, long pstr, int spmask)
{
  int t = threadIdx.x;
  int rh = t >> 7;                            // which of the block's 2 rows
  long row = (long)blockIdx.x * 2 + rh;       // 0..8191
  int sel = row >= 4096;
  long r = row & 4095;
  const float* x  = sel ? x1 : x0;
  const float* g  = sel ? g1 : g0;
  const float* bb = sel ? b1 : b0;
  float* yf = sel ? yf1 : yf0;
  bf16*  yb = sel ? yb1 : yb0;
  int single = (spmask >> sel) & 1;
  int c = (t & 127) * 4;
  const float* xr = x + r * D_ + c;
  const float* ra = P + (sel ? 2 : 0) * pstr + r * D_ + c;
  const float* rb = ra + pstr;
  float4 xv = *(const float4*)xr;
  float4 av = *(const float4*)ra;
  float4 v = { xv.x + av.x, xv.y + av.y, xv.z + av.z, xv.w + av.w };
  if (!single) {
    float4 bv = *(const float4*)rb;
    v.x += bv.x; v.y += bv.y; v.z += bv.z; v.w += bv.w;
  }
  float s  = v.x + v.y + v.z + v.w;
  float ss = v.x * v.x + v.y * v.y + v.z * v.z + v.w * v.w;
#pragma unroll
  for (int o = 32; o > 0; o >>= 1) {
    s  += __shfl_down(s, o, 64);
    ss += __shfl_down(ss, o, 64);
  }
  __shared__ float rs[4];
  __shared__ float rss[4];
  int lane = t & 63, wid = t >> 6;
  if (lane == 0) { rs[wid] = s; rss[wid] = ss; }
  __syncthreads();
  s  = rs[rh * 2]  + rs[rh * 2 + 1];
  ss = rss[rh * 2] + rss[rh * 2 + 1];
  float mean = s * (1.0f / D_);
  float var = ss * (1.0f / D_) - mean * mean;
  float rstd = rsqrtf(var + 1e-5f);
  float4 gg = *(const float4*)(g + c);
  float4 b4 = *(const float4*)(bb + c);
  float4 o4 = { (v.x - mean) * rstd * gg.x + b4.x,
                (v.y - mean) * rstd * gg.y + b4.y,
                (v.z - mean) * rstd * gg.z + b4.z,
                (v.w - mean) * rstd * gg.w + b4.w };
  if (yf) *(float4*)(yf + r * D_ + c) = o4;
  if (yb) {
    bf16 ov[4] = { __float2bfloat16(o4.x), __float2bfloat16(o4.y),
                   __float2bfloat16(o4.z), __float2bfloat16(o4.w) };
    *(short4v*)&yb[r * D_ + c] = *(const short4v*)ov;
  }
}

// ---------------- wave-per-row cross-masked softmax (final pooling) ----------------
__global__ __launch_bounds__(256) void k_softmax_x(float* __restrict__ S,
                                                   const int* __restrict__ vm,
                                                   const int* __restrict__ qm)
{
  int wrow = blockIdx.x * 4 + (threadIdx.x >> 6);
  int lane = threadIdx.x & 63;
  int b = wrow >> 9, i = wrow & 511;
  bool rowpad = (vm[(b << 9) + i] == 0);
  float* p = S + (long)wrow * 512;
  const int* qb = qm + (b << 9);
  int j0 = lane * 8;
  float4 a0 = *(const float4*)(p + j0);
  float4 a1 = *(const float4*)(p + j0 + 4);
  int4 m0 = *(const int4*)(qb + j0);
  int4 m1 = *(const int4*)(qb + j0 + 4);
  float v[8];
  v[0] = (rowpad || !m0.x) ? -1e9f : a0.x; v[1] = (rowpad || !m0.y) ? -1e9f : a0.y;
  v[2] = (rowpad || !m0.z) ? -1e9f : a0.z; v[3] = (rowpad || !m0.w) ? -1e9f : a0.w;
  v[4] = (rowpad || !m1.x) ? -1e9f : a1.x; v[5] = (rowpad || !m1.y) ? -1e9f : a1.y;
  v[6] = (rowpad || !m1.z) ? -1e9f : a1.z; v[7] = (rowpad || !m1.w) ? -1e9f : a1.w;
  float mx = v[0];
#pragma unroll
  for (int u = 1; u < 8; ++u) mx = fmaxf(mx, v[u]);
#pragma unroll
  for (int o = 1; o < 64; o <<= 1) mx = fmaxf(mx, __shfl_xor(mx, o, 64));
  float e[8], sum = 0.f;
#pragma unroll
  for (int u = 0; u < 8; ++u) { e[u] = __expf(v[u] - mx); sum += e[u]; }
#pragma unroll
  for (int o = 1; o < 64; o <<= 1) sum += __shfl_xor(sum, o, 64);
  float inv = 1.0f / sum;
  bf16 ob[8];
#pragma unroll
  for (int u = 0; u < 8; ++u) ob[u] = __float2bfloat16(e[u] * inv);
  bf16* pb = (bf16*)p;
  *(short8*)&pb[j0] = *(const short8*)ob;
}

// ---------------- final prep: Vw = bf16(V*w); Qt = bf16(Q^T) per batch ----------------
__global__ __launch_bounds__(256) void k_vwqt(const float* __restrict__ V,
                                              const float* __restrict__ Q,
                                              const float* __restrict__ w,
                                              bf16* __restrict__ Vw, bf16* __restrict__ Qt)
{
  __shared__ float Ls[32][33];
  int bx = blockIdx.x, t = threadIdx.x;
  if (bx < 2048) {
    int i = bx * 1024 + t * 4;
    float4 v = *(const float4*)(V + i);
    int k = i & 511;
    bf16 o[4] = { __float2bfloat16(v.x * w[k]),     __float2bfloat16(v.y * w[k + 1]),
                  __float2bfloat16(v.z * w[k + 2]), __float2bfloat16(v.w * w[k + 3]) };
    *(short4v*)&Vw[i] = *(const short4v*)o;
  } else {
    int q = bx - 2048; int b = q >> 8; int tq = q & 255;
    int tr = tq >> 4, tc = tq & 15;
    const float* Qb = Q + (long)b * 262144;
    bf16* Qtb = Qt + (long)b * 262144;
    int lr = t >> 3, lc0 = (t & 7) * 4;
    float4 v = *(const float4*)(Qb + (long)(tr * 32 + lr) * 512 + tc * 32 + lc0);
    Ls[lr][lc0] = v.x; Ls[lr][lc0 + 1] = v.y; Ls[lr][lc0 + 2] = v.z; Ls[lr][lc0 + 3] = v.w;
    __syncthreads();
    bf16 ov[4];
#pragma unroll
    for (int j = 0; j < 4; ++j) ov[j] = __float2bfloat16(Ls[lc0 + j][lr]);
    *(short4v*)&Qtb[(long)(tc * 32 + lr) * 512 + tr * 32 + lc0] = *(const short4v*)ov;
  }
}

// ---------------- out[b,k] = (1/512) * sum_i V[b,i,k] * T[b,i,k] ----------------
// split over 16 i-segments x 2 k-halves x 8 batches = 256 blocks -> partials, then reduce
__global__ __launch_bounds__(256) void k_final_part(
    const float* __restrict__ V, const float* __restrict__ QT, float* __restrict__ Pf)
{
  int bx = blockIdx.x;
  int b = bx >> 5, rem = bx & 31;
  int kc = rem >> 4, is = rem & 15;
  int k = (kc << 8) + threadIdx.x;
  const float* Vb = V  + (long)b * N_ * D_ + (long)(is * 32) * D_ + k;
  const float* Tb = QT + (long)b * N_ * D_ + (long)(is * 32) * D_ + k;
  float acc = 0.0f;
#pragma unroll 8
  for (int i = 0; i < 32; ++i) acc += Vb[(long)i * D_] * Tb[(long)i * D_];
  Pf[bx * 256 + threadIdx.x] = acc;
}

__global__ __launch_bounds__(256) void k_fred(const float* __restrict__ Pf,
                                              float* __restrict__ out)
{
  int b = blockIdx.x >> 1, kc = blockIdx.x & 1;
  int k = (kc << 8) + threadIdx.x;
  float s = 0.0f;
#pragma unroll
  for (int is = 0; is < 16; ++is)
    s += Pf[(((b << 5) | (kc << 4) | is) << 8) + threadIdx.x];
  out[b * D_ + k] = s * (1.0f / 512.0f);
}

extern "C" void kernel_launch(void* const* d_in, const int* in_sizes, int n_in,
                              void* d_out, int out_size, void* d_ws, size_t ws_size,
                              hipStream_t stream)
{
  const float* in_v   = (const float*)d_in[0];
  const float* in_q   = (const float*)d_in[1];
  const int*   v_mask = (const int*)  d_in[2];
  const int*   q_mask = (const int*)  d_in[3];
  const float* aw  = (const float*)d_in[4];
  const float* ab  = (const float*)d_in[5];
  const float* awo = (const float*)d_in[6];
  const float* abo = (const float*)d_in[7];
  const float* lg  = (const float*)d_in[8];
  const float* lb  = (const float*)d_in[9];
  const float* fw1 = (const float*)d_in[10];
  const float* fb1 = (const float*)d_in[11];
  const float* fw2 = (const float*)d_in[12];
  const float* fb2 = (const float*)d_in[13];
  const float* atw = (const float*)d_in[14];
  const float* atb = (const float*)d_in[15];
  float* out = (float*)d_out;
  (void)atb;  // softmax is shift-invariant

  const int SZ = B_ * N_ * D_;
  char* wsb = (char*)d_ws;
  const long MB = 1024L * 1024;
  float* Vcur   = (float*)(wsb + 0 * MB);
  float* Qcur   = (float*)(wsb + 8 * MB);
  float* P0     = (float*)(wsb + 16 * MB);
  const long PSZ = 2097152;               // floats per partial (8 MB)
  bf16*  WT     = (bf16*) (wsb + 48 * MB);
  bf16*  Vcur_b = (bf16*) (wsb + 64 * MB);
  bf16*  Qcur_b = (bf16*) (wsb + 68 * MB);
  bf16*  VA_b   = (bf16*) (wsb + 72 * MB);
  bf16*  QA_b   = (bf16*) (wsb + 76 * MB);
  bf16*  VQ_b   = (bf16*) (wsb + 80 * MB);
  bf16*  QKV0   = (bf16*) (wsb + 84 * MB);
  bf16*  Hid    = (bf16*) (wsb + 108 * MB);
  float* Sf     = P0;
  bf16*  Vw_b   = (bf16*) (wsb + 24 * MB);
  bf16*  Qt_b   = (bf16*) (wsb + 28 * MB);
  float* Tfin   = (float*)(wsb + 32 * MB);
  float* Pf     = (float*)(wsb + 41 * MB);   // 256 KB final-pool partials

  const long ZBIG = 1000000;

  k_prep2<<<4096, 256, 0, stream>>>(in_v, Vcur, Vcur_b, in_q, Qcur, Qcur_b, SZ / 4);

  for (int l = 0; l < L_; ++l) {
    const float* lgl = lg + (long)l * 6 * D_;
    const float* lbl = lb + (long)l * 6 * D_;
    k_wt<<<8192, 256, 0, stream>>>(aw + (long)l * 12 * 262144,
                                   awo + (long)l * 4 * 262144,
                                   fw1 + (long)l * 2 * 1048576,
                                   fw2 + (long)l * 2 * 1048576, WT);
    // ---- self-attention (2 streams: s0=v, s1=q) ----
    k_mfma<128><<<dim3(12, 32, 2), 256, 0, stream>>>(
        Vcur_b, Vcur_b, 2097152, 0, 0, 512,
        WT, 1048576, 0, 0, 512,
        ab + (long)l * 4 * 1536, 1536, 1.f, 0,
        nullptr, 0, 0, 0, 0, QKV0, 6291456, 0, 0, 0,
        512, 1, 1, 1, 1, 0);
    k_flash<<<dim3(8, 64, 2), 256, 0, stream>>>(QKV0, 6291456, v_mask, q_mask, 0.125f);
    k_mfma<128><<<dim3(4, 32, 4), 256, 0, stream>>>(      // out-proj, splitK=2 x 2 streams
        QKV0, QKV0, 6291456, 0, 0, 512,
        WT + 3 * 262144, 1048576, 0, 0, 512,
        abo + (long)l * 4 * 512, 512, 1.f, 0,
        P0, 2 * PSZ, 0, 0, 512, nullptr, 0, 0, 0, 0,
        256, 1, 1, 0, 2, PSZ);
    k_ln2<<<4096, 256, 0, stream>>>(Vcur, lgl + 0 * D_, lbl + 0 * D_, nullptr, VA_b,
                                    Qcur, lgl + 1 * D_, lbl + 1 * D_, nullptr, QA_b,
                                    P0, PSZ, 0);
    // ---- cross attention vq: xq=VA, xkv=QA ----
    k_mfma<128><<<dim3(12, 32, 1), 256, 0, stream>>>(
        VA_b, QA_b, 0, 0, 0, 512,
        WT + 2 * 1048576, 0, 0, 0, 512,
        ab + (long)(l * 4 + 2) * 1536, 0, 1.f, 0,
        nullptr, 0, 0, 0, 0, QKV0, 0, 0, 0, 0,
        512, 1, 1, 1, 1, 0);
    k_flash<<<dim3(8, 64, 1), 256, 0, stream>>>(QKV0, 0, q_mask, q_mask, 0.125f);
    k_mfma<64><<<dim3(8, 32, 1), 256, 0, stream>>>(       // out-proj vq, UNSPLIT: P0 fp32 + VQ_b bf16
        QKV0, QKV0, 0, 0, 0, 512,
        WT + (2 * 4 + 3) * 262144, 0, 0, 0, 512,
        abo + (long)(l * 4 + 2) * 512, 0, 1.f, 0,
        P0, 0, 0, 0, 512, VQ_b, 0, 0, 0, 512,
        512, 1, 1, 0, 1, 0);
    // ---- cross attention qv: xq=QA, xkv=VQ ----
    k_mfma<128><<<dim3(12, 32, 1), 256, 0, stream>>>(
        QA_b, VQ_b, 0, 0, 0, 512,
        WT + 3 * 1048576, 0, 0, 0, 512,
        ab + (long)(l * 4 + 3) * 1536, 0, 1.f, 0,
        nullptr, 0, 0, 0, 0, QKV0, 0, 0, 0, 0,
        512, 1, 1, 1, 1, 0);
    k_flash<<<dim3(8, 64, 1), 256, 0, stream>>>(QKV0, 0, v_mask, v_mask, 0.125f);
    k_mfma<64><<<dim3(8, 32, 2), 256, 0, stream>>>(       // out-proj qv -> P2,P3
        QKV0, QKV0, 0, 0, 0, 512,
        WT + (3 * 4 + 3) * 262144, 0, 0, 0, 512,
        abo + (long)(l * 4 + 3) * 512, 0, 1.f, 0,
        P0 + 2 * PSZ, 0, 0, 0, 512, nullptr, 0, 0, 0, 0,
        256, 1, 1, 0, 2, PSZ);
    k_ln2<<<4096, 256, 0, stream>>>(Vcur, lgl + 2 * D_, lbl + 2 * D_, Vcur, Vcur_b,
                                    Qcur, lgl + 3 * D_, lbl + 3 * D_, Qcur, Qcur_b,
                                    P0, PSZ, 1);
    // ---- FFN (2 streams) ----
    k_mfma<128><<<dim3(16, 32, 2), 256, 0, stream>>>(
        Vcur_b, Vcur_b, 2097152, 0, 0, 512,
        WT + 4194304, 1048576, 0, 0, 512,
        fb1 + (long)l * 2 * 2048, 2048, 1.f, 1,
        nullptr, 0, 0, 0, 0, Hid, 8388608, 0, 0, 2048,
        512, 1, 1, 0, 1, 0);
    k_mfma<128><<<dim3(4, 32, 4), 256, 0, stream>>>(      // fc2 splitK=2 x 2 streams
        Hid, Hid, 8388608, 0, 0, 2048,
        WT + 6291456, 1048576, 0, 0, 2048,
        fb2 + (long)l * 2 * 512, 512, 1.f, 0,
        P0, 2 * PSZ, 0, 0, 512, nullptr, 0, 0, 0, 0,
        1024, 1, 1, 0, 2, PSZ);
    k_ln2<<<4096, 256, 0, stream>>>(Vcur, lgl + 4 * D_, lbl + 4 * D_, Vcur, Vcur_b,
                                    Qcur, lgl + 5 * D_, lbl + 5 * D_, Qcur, Qcur_b,
                                    P0, PSZ, 0);
  }

  // ---- final bilinear attention pooling ----
  k_vwqt<<<4096, 256, 0, stream>>>(Vcur, Qcur, atw, Vw_b, Qt_b);
  k_mfma<128><<<dim3(4, 4, 8), 256, 0, stream>>>(          // scores = (V*w) @ Q^T -> Sf(=P0)
      Vw_b, Vw_b, 0, 262144, 0, 512, Qcur_b, 0, 262144, 0, 512,
      nullptr, 0, 1.f, 0,
      Sf, 0, 262144, 0, 512, nullptr, 0, 0, 0, 0,
      512, 1, ZBIG, 0, 1, 0);
  k_softmax_x<<<1024, 256, 0, stream>>>(Sf, v_mask, q_mask);
  k_mfma<128><<<dim3(4, 4, 8), 256, 0, stream>>>(          // Tfin = P @ Q
      (const bf16*)Sf, (const bf16*)Sf, 0, 524288, 0, 1024, Qt_b, 0, 262144, 0, 512,
      nullptr, 0, 1.f, 0,
      Tfin, 0, 262144, 0, 512, nullptr, 0, 0, 0, 0,
      512, 1, ZBIG, 0, 1, 0);
  k_final_part<<<256, 256, 0, stream>>>(Vcur, Tfin, Pf);
  k_fred<<<16, 256, 0, stream>>>(Pf, out);

  (void)in_sizes; (void)n_in; (void)out_size; (void)ws_size;
}